// Round 1
// baseline (799.988 us; speedup 1.0000x reference)
//
#include <hip/hip_runtime.h>

// Pipeline: feature extraction (3 convs x 2 images), then per scale:
//   off_feat = relu(conv3x3(cat(ref_f, unr_f), off_w, pad=1))
//   fused kernel: offsets = conv3x3(off_feat, dcn_off_w, pad=1) computed
//   on-the-fly per pixel, then deformable conv of unr_f -> aligned[i].

// ---------------- weight transpose: [Cout][Cin][9] -> [Cin*9][Cout] ----------
__global__ void transpose_w_k(const float* __restrict__ w, float* __restrict__ wT,
                              int Cout, int Cin) {
    int idx = blockIdx.x * blockDim.x + threadIdx.x;
    int total = Cout * Cin * 9;
    if (idx >= total) return;
    int t  = idx % 9;
    int ci = (idx / 9) % Cin;
    int co = idx / (9 * Cin);
    wT[(ci * 9 + t) * Cout + co] = w[idx];
}

// ---------------- generic 3x3 conv, Cout=16, optional concat input ----------
template <int CIN, bool PAD1, bool RELU>
__launch_bounds__(256)
__global__ void conv3x3_k(const float* __restrict__ in0,
                          const float* __restrict__ in1,   // channels 16..31 (CIN==32)
                          const float* __restrict__ wT,    // [CIN*9][16]
                          const float* __restrict__ bias,  // [16]
                          float* __restrict__ out,
                          int H, int W, int OH, int OW) {
    __shared__ float tile[CIN * 18 * 18];
    const int tid = threadIdx.x;
    const int tx0 = blockIdx.x * 16, ty0 = blockIdx.y * 16;
    const int b = blockIdx.z;
    const int bx = tx0 - (PAD1 ? 1 : 0), by = ty0 - (PAD1 ? 1 : 0);

    for (int idx = tid; idx < CIN * 324; idx += 256) {
        int ci  = idx / 324;
        int rem = idx - ci * 324;
        int r = rem / 18, c = rem - r * 18;
        int gy = by + r, gx = bx + c;
        float v = 0.f;
        if (gy >= 0 && gy < H && gx >= 0 && gx < W) {
            if (CIN == 32 && ci >= 16)
                v = in1[((size_t)(b * 16 + ci - 16) * H + gy) * W + gx];
            else
                v = in0[((size_t)(b * 16 + ci) * H + gy) * W + gx];
        }
        tile[idx] = v;
    }
    __syncthreads();

    const int ox = tid & 15, oy = tid >> 4;
    float acc[16];
#pragma unroll
    for (int co = 0; co < 16; ++co) acc[co] = bias[co];

#pragma unroll 1
    for (int ci = 0; ci < CIN; ++ci) {
        const float* tc = &tile[ci * 324];
#pragma unroll
        for (int t = 0; t < 9; ++t) {
            float v = tc[(oy + t / 3) * 18 + ox + (t % 3)];
            const float* wrow = &wT[(ci * 9 + t) * 16];
#pragma unroll
            for (int co = 0; co < 16; ++co) acc[co] += v * wrow[co];
        }
    }

    const int gy = ty0 + oy, gx = tx0 + ox;
    if (gy < OH && gx < OW) {
#pragma unroll
        for (int co = 0; co < 16; ++co) {
            float r = RELU ? fmaxf(acc[co], 0.f) : acc[co];
            out[((size_t)(b * 16 + co) * OH + gy) * OW + gx] = r;
        }
    }
}

// ---------------- fused dcn-offset conv (pad=1, 16->144) + deform conv ------
__launch_bounds__(256)
__global__ void deform_fused_k(const float* __restrict__ x,     // unr_f [B,16,H,W]
                               const float* __restrict__ offF,  // off_feat [B,16,H,W]
                               const float* __restrict__ owT,   // [16*9][144]
                               const float* __restrict__ ob,    // [144]
                               const float* __restrict__ dwT,   // [16*9][16]
                               const float* __restrict__ db,    // [16]
                               float* __restrict__ out,         // [B,16,H,W]
                               int H, int W) {
    __shared__ float tile[16 * 18 * 18];
    const int tid = threadIdx.x;
    const int tx0 = blockIdx.x * 16, ty0 = blockIdx.y * 16;
    const int b = blockIdx.z;
    const int bx = tx0 - 1, by = ty0 - 1;

    for (int idx = tid; idx < 16 * 324; idx += 256) {
        int ci  = idx / 324;
        int rem = idx - ci * 324;
        int r = rem / 18, c = rem - r * 18;
        int gy = by + r, gx = bx + c;
        float v = 0.f;
        if (gy >= 0 && gy < H && gx >= 0 && gx < W)
            v = offF[((size_t)(b * 16 + ci) * H + gy) * W + gx];
        tile[idx] = v;
    }
    __syncthreads();

    const int ox = tid & 15, oy = tid >> 4;
    const int gy = ty0 + oy, gx = tx0 + ox;
    const int HW = H * W;

    float acc[16];
#pragma unroll
    for (int co = 0; co < 16; ++co) acc[co] = db[co];

#pragma unroll 1
    for (int dg = 0; dg < 8; ++dg) {
        // ---- offsets for this deform group: 18 values (y,x per 9 taps) ----
        float offv[18];
#pragma unroll
        for (int j = 0; j < 18; ++j) offv[j] = ob[dg * 18 + j];

#pragma unroll 1
        for (int ci = 0; ci < 16; ++ci) {
            const float* tc = &tile[ci * 324];
#pragma unroll
            for (int t = 0; t < 9; ++t) {
                float v = tc[(oy + t / 3) * 18 + ox + (t % 3)];
                const float* wrow = &owT[(ci * 9 + t) * 144 + dg * 18];
#pragma unroll
                for (int j = 0; j < 18; ++j) offv[j] += v * wrow[j];
            }
        }

        // ---- bilinear sampling + accumulate into 16 output channels ----
        const float* xb = x + (size_t)(b * 16 + dg * 2) * HW;
#pragma unroll
        for (int k = 0; k < 9; ++k) {
            float sy = (float)(gy + k / 3 - 1) + offv[2 * k];
            float sx = (float)(gx + (k % 3) - 1) + offv[2 * k + 1];
            float fy = floorf(sy), fx = floorf(sx);
            int y0 = (int)fy, x0 = (int)fx;
            float wy = sy - fy, wx = sx - fx;
            bool y0v = (y0 >= 0) && (y0 < H);
            bool y1v = (y0 + 1 >= 0) && (y0 + 1 < H);
            bool x0v = (x0 >= 0) && (x0 < W);
            bool x1v = (x0 + 1 >= 0) && (x0 + 1 < W);
            int i00 = y0 * W + x0;
#pragma unroll
            for (int c2 = 0; c2 < 2; ++c2) {
                const float* p = xb + c2 * HW;
                float v00 = (y0v && x0v) ? p[i00] : 0.f;
                float v01 = (y0v && x1v) ? p[i00 + 1] : 0.f;
                float v10 = (y1v && x0v) ? p[i00 + W] : 0.f;
                float v11 = (y1v && x1v) ? p[i00 + W + 1] : 0.f;
                float top = v00 + (v01 - v00) * wx;
                float bot = v10 + (v11 - v10) * wx;
                float s = top + (bot - top) * wy;
                const float* wrow = &dwT[((dg * 2 + c2) * 9 + k) * 16];
#pragma unroll
                for (int co = 0; co < 16; ++co) acc[co] += s * wrow[co];
            }
        }
    }

    if (gy < H && gx < W) {
#pragma unroll
        for (int co = 0; co < 16; ++co)
            out[((size_t)(b * 16 + co) * H + gy) * W + gx] = acc[co];
    }
}

// ---------------------------------------------------------------------------
extern "C" void kernel_launch(void* const* d_in, const int* in_sizes, int n_in,
                              void* d_out, int out_size, void* d_ws, size_t ws_size,
                              hipStream_t stream) {
    const float* ref_image = (const float*)d_in[0];
    const float* unreg_image = (const float*)d_in[1];
    const float* fe_w1 = (const float*)d_in[2];
    const float* fe_b1 = (const float*)d_in[3];
    const float* fe_w2 = (const float*)d_in[4];
    const float* fe_b2 = (const float*)d_in[5];
    const float* fe_w3 = (const float*)d_in[6];
    const float* fe_b3 = (const float*)d_in[7];
    const float* off_w0 = (const float*)d_in[8];
    const float* off_b0 = (const float*)d_in[9];
    const float* off_w1 = (const float*)d_in[10];
    const float* off_b1 = (const float*)d_in[11];
    const float* off_w2 = (const float*)d_in[12];
    const float* off_b2 = (const float*)d_in[13];
    const float* dcn_off_w = (const float*)d_in[14];
    const float* dcn_off_b = (const float*)d_in[15];
    const float* dcn_w = (const float*)d_in[16];
    const float* dcn_b = (const float*)d_in[17];

    const int B = 4;
    const size_t sz1 = (size_t)B * 16 * 192 * 192;
    const size_t sz2 = (size_t)B * 16 * 190 * 190;
    const size_t sz3 = (size_t)B * 16 * 188 * 188;

    float* p = (float*)d_ws;
    float* ref_f1 = p; p += sz1;
    float* unr_f1 = p; p += sz1;
    float* ref_f2 = p; p += sz2;
    float* unr_f2 = p; p += sz2;
    float* ref_f3 = p; p += sz3;
    float* unr_f3 = p; p += sz3;
    float* off_feat = p; p += sz1;
    float* wT_fe1 = p; p += 16 * 16 * 9;
    float* wT_fe2 = p; p += 16 * 16 * 9;
    float* wT_fe3 = p; p += 16 * 16 * 9;
    float* wT_off0 = p; p += 16 * 32 * 9;
    float* wT_off1 = p; p += 16 * 32 * 9;
    float* wT_off2 = p; p += 16 * 32 * 9;
    float* owT = p; p += 144 * 16 * 9;
    float* dwT = p; p += 16 * 16 * 9;

    float* out0 = (float*)d_out;
    float* out1 = out0 + sz1;
    float* out2 = out1 + sz2;

    // ---- weight transposes ----
    {
        dim3 blk(256);
        transpose_w_k<<<dim3((16 * 16 * 9 + 255) / 256), blk, 0, stream>>>(fe_w1, wT_fe1, 16, 16);
        transpose_w_k<<<dim3((16 * 16 * 9 + 255) / 256), blk, 0, stream>>>(fe_w2, wT_fe2, 16, 16);
        transpose_w_k<<<dim3((16 * 16 * 9 + 255) / 256), blk, 0, stream>>>(fe_w3, wT_fe3, 16, 16);
        transpose_w_k<<<dim3((16 * 32 * 9 + 255) / 256), blk, 0, stream>>>(off_w0, wT_off0, 16, 32);
        transpose_w_k<<<dim3((16 * 32 * 9 + 255) / 256), blk, 0, stream>>>(off_w1, wT_off1, 16, 32);
        transpose_w_k<<<dim3((16 * 32 * 9 + 255) / 256), blk, 0, stream>>>(off_w2, wT_off2, 16, 32);
        transpose_w_k<<<dim3((144 * 16 * 9 + 255) / 256), blk, 0, stream>>>(dcn_off_w, owT, 144, 16);
        transpose_w_k<<<dim3((16 * 16 * 9 + 255) / 256), blk, 0, stream>>>(dcn_w, dwT, 16, 16);
    }

    dim3 blk(256);
    dim3 g192(12, 12, B);   // 192/16
    dim3 g190(12, 12, B);   // ceil(190/16)
    dim3 g188(12, 12, B);   // ceil(188/16)

    // ---- feature extraction ----
    conv3x3_k<16, true, true><<<g192, blk, 0, stream>>>(ref_image, nullptr, wT_fe1, fe_b1, ref_f1, 192, 192, 192, 192);
    conv3x3_k<16, true, true><<<g192, blk, 0, stream>>>(unreg_image, nullptr, wT_fe1, fe_b1, unr_f1, 192, 192, 192, 192);
    conv3x3_k<16, false, true><<<g190, blk, 0, stream>>>(ref_f1, nullptr, wT_fe2, fe_b2, ref_f2, 192, 192, 190, 190);
    conv3x3_k<16, false, true><<<g190, blk, 0, stream>>>(unr_f1, nullptr, wT_fe2, fe_b2, unr_f2, 192, 192, 190, 190);
    conv3x3_k<16, false, true><<<g188, blk, 0, stream>>>(ref_f2, nullptr, wT_fe3, fe_b3, ref_f3, 190, 190, 188, 188);
    conv3x3_k<16, false, true><<<g188, blk, 0, stream>>>(unr_f2, nullptr, wT_fe3, fe_b3, unr_f3, 190, 190, 188, 188);

    // ---- scale 0 (192) ----
    conv3x3_k<32, true, true><<<g192, blk, 0, stream>>>(ref_f1, unr_f1, wT_off0, off_b0, off_feat, 192, 192, 192, 192);
    deform_fused_k<<<g192, blk, 0, stream>>>(unr_f1, off_feat, owT, dcn_off_b, dwT, dcn_b, out0, 192, 192);

    // ---- scale 1 (190) ----
    conv3x3_k<32, true, true><<<g190, blk, 0, stream>>>(ref_f2, unr_f2, wT_off1, off_b1, off_feat, 190, 190, 190, 190);
    deform_fused_k<<<g190, blk, 0, stream>>>(unr_f2, off_feat, owT, dcn_off_b, dwT, dcn_b, out1, 190, 190);

    // ---- scale 2 (188) ----
    conv3x3_k<32, true, true><<<g188, blk, 0, stream>>>(ref_f3, unr_f3, wT_off2, off_b2, off_feat, 188, 188, 188, 188);
    deform_fused_k<<<g188, blk, 0, stream>>>(unr_f3, off_feat, owT, dcn_off_b, dwT, dcn_b, out2, 188, 188);
}

// Round 2
// 677.919 us; speedup vs baseline: 1.1801x; 1.1801x over previous
//
#include <hip/hip_runtime.h>

// Pipeline (batched dispatches):
//  1. transpose_all_k          — all 8 weight transposes, one launch
//  2. conv_fe_k level1 (z=8)   — ref+unreg images in one launch
//  3. conv_fe_k level2 (z=8)
//  4. conv_fe_k level3 (z=8)
//  5. conv_off_k (z=12)        — all 3 scales' offset-feature convs
//  6. deform_all_k (z=12)      — all 3 scales' fused offset-conv + deform conv

// ---------------- all weight transposes: [Cout][Cin][9] -> [Cin*9][Cout] ----
__global__ void transpose_all_k(
    const float* __restrict__ fe_w1, const float* __restrict__ fe_w2,
    const float* __restrict__ fe_w3, const float* __restrict__ off_w0,
    const float* __restrict__ off_w1, const float* __restrict__ off_w2,
    const float* __restrict__ dcn_off_w, const float* __restrict__ dcn_w,
    float* __restrict__ wT_fe1, float* __restrict__ wT_fe2,
    float* __restrict__ wT_fe3, float* __restrict__ wT_off0,
    float* __restrict__ wT_off1, float* __restrict__ wT_off2,
    float* __restrict__ owT, float* __restrict__ dwT) {
    const float* w; float* wT; int Cout, Cin;
    switch (blockIdx.y) {
        case 0: w = fe_w1;     wT = wT_fe1;  Cout = 16;  Cin = 16; break;
        case 1: w = fe_w2;     wT = wT_fe2;  Cout = 16;  Cin = 16; break;
        case 2: w = fe_w3;     wT = wT_fe3;  Cout = 16;  Cin = 16; break;
        case 3: w = off_w0;    wT = wT_off0; Cout = 16;  Cin = 32; break;
        case 4: w = off_w1;    wT = wT_off1; Cout = 16;  Cin = 32; break;
        case 5: w = off_w2;    wT = wT_off2; Cout = 16;  Cin = 32; break;
        case 6: w = dcn_off_w; wT = owT;     Cout = 144; Cin = 16; break;
        default: w = dcn_w;    wT = dwT;     Cout = 16;  Cin = 16; break;
    }
    int idx = blockIdx.x * 256 + threadIdx.x;
    if (idx >= Cout * Cin * 9) return;
    int t  = idx % 9;
    int ci = (idx / 9) % Cin;
    int co = idx / (9 * Cin);
    wT[(ci * 9 + t) * Cout + co] = w[idx];
}

// ---------------- FE conv: CIN=16, both images in one launch ----------------
template <bool PAD1>
__launch_bounds__(256)
__global__ void conv_fe_k(const float* __restrict__ inA, const float* __restrict__ inB,
                          const float* __restrict__ wT,   // [16*9][16]
                          const float* __restrict__ bias,
                          float* __restrict__ outA, float* __restrict__ outB,
                          int H, int W, int OH, int OW) {
    __shared__ float tile[16 * 324];
    const int tid = threadIdx.x;
    const int tx0 = blockIdx.x * 16, ty0 = blockIdx.y * 16;
    const int b = blockIdx.z & 3;
    const int img = blockIdx.z >> 2;
    const float* in = img ? inB : inA;
    float* out = img ? outB : outA;
    const int bx = tx0 - (PAD1 ? 1 : 0), by = ty0 - (PAD1 ? 1 : 0);

    for (int idx = tid; idx < 16 * 324; idx += 256) {
        int ci  = idx / 324;
        int rem = idx - ci * 324;
        int r = rem / 18, c = rem - r * 18;
        int gy = by + r, gx = bx + c;
        float v = 0.f;
        if (gy >= 0 && gy < H && gx >= 0 && gx < W)
            v = in[((size_t)(b * 16 + ci) * H + gy) * W + gx];
        tile[idx] = v;
    }
    __syncthreads();

    const int ox = tid & 15, oy = tid >> 4;
    float acc[16];
#pragma unroll
    for (int co = 0; co < 16; ++co) acc[co] = bias[co];

#pragma unroll 1
    for (int ci = 0; ci < 16; ++ci) {
        const float* tc = &tile[ci * 324];
#pragma unroll
        for (int t = 0; t < 9; ++t) {
            float v = tc[(oy + t / 3) * 18 + ox + (t % 3)];
            const float* wrow = &wT[(ci * 9 + t) * 16];
#pragma unroll
            for (int co = 0; co < 16; ++co) acc[co] += v * wrow[co];
        }
    }

    const int gy = ty0 + oy, gx = tx0 + ox;
    if (gy < OH && gx < OW) {
#pragma unroll
        for (int co = 0; co < 16; ++co)
            out[((size_t)(b * 16 + co) * OH + gy) * OW + gx] = fmaxf(acc[co], 0.f);
    }
}

// ---------------- offset-feature conv: CIN=32 (chunked), 3 scales ------------
__launch_bounds__(256)
__global__ void conv_off_k(const float* __restrict__ r0, const float* __restrict__ r1,
                           const float* __restrict__ r2, const float* __restrict__ u0,
                           const float* __restrict__ u1, const float* __restrict__ u2,
                           const float* __restrict__ w0, const float* __restrict__ w1,
                           const float* __restrict__ w2, const float* __restrict__ b0,
                           const float* __restrict__ b1, const float* __restrict__ b2,
                           float* __restrict__ o0, float* __restrict__ o1,
                           float* __restrict__ o2) {
    const int s = blockIdx.z >> 2;
    const int b = blockIdx.z & 3;
    const int H = 192 - 2 * s, W = H;
    const float* inR  = s == 0 ? r0 : (s == 1 ? r1 : r2);
    const float* inU  = s == 0 ? u0 : (s == 1 ? u1 : u2);
    const float* wT   = s == 0 ? w0 : (s == 1 ? w1 : w2);
    const float* bias = s == 0 ? b0 : (s == 1 ? b1 : b2);
    float* out        = s == 0 ? o0 : (s == 1 ? o1 : o2);

    __shared__ float tile[16 * 324];
    const int tid = threadIdx.x;
    const int tx0 = blockIdx.x * 16, ty0 = blockIdx.y * 16;
    const int bx = tx0 - 1, by = ty0 - 1;
    const int ox = tid & 15, oy = tid >> 4;

    float acc[16];
#pragma unroll
    for (int co = 0; co < 16; ++co) acc[co] = bias[co];

#pragma unroll 1
    for (int chunk = 0; chunk < 2; ++chunk) {
        const float* in = chunk ? inU : inR;
        if (chunk) __syncthreads();
        for (int idx = tid; idx < 16 * 324; idx += 256) {
            int ci  = idx / 324;
            int rem = idx - ci * 324;
            int r = rem / 18, c = rem - r * 18;
            int gy = by + r, gx = bx + c;
            float v = 0.f;
            if (gy >= 0 && gy < H && gx >= 0 && gx < W)
                v = in[((size_t)(b * 16 + ci) * H + gy) * W + gx];
            tile[idx] = v;
        }
        __syncthreads();

#pragma unroll 1
        for (int ci = 0; ci < 16; ++ci) {
            const float* tc = &tile[ci * 324];
#pragma unroll
            for (int t = 0; t < 9; ++t) {
                float v = tc[(oy + t / 3) * 18 + ox + (t % 3)];
                const float* wrow = &wT[((chunk * 16 + ci) * 9 + t) * 16];
#pragma unroll
                for (int co = 0; co < 16; ++co) acc[co] += v * wrow[co];
            }
        }
    }

    const int gy = ty0 + oy, gx = tx0 + ox;
    if (gy < H && gx < W) {
#pragma unroll
        for (int co = 0; co < 16; ++co)
            out[((size_t)(b * 16 + co) * H + gy) * W + gx] = fmaxf(acc[co], 0.f);
    }
}

// ---------------- fused dcn-offset conv + deform conv, 3 scales -------------
__launch_bounds__(256)
__global__ void deform_all_k(const float* __restrict__ x0, const float* __restrict__ x1,
                             const float* __restrict__ x2, const float* __restrict__ f0,
                             const float* __restrict__ f1, const float* __restrict__ f2,
                             const float* __restrict__ owT,  // [16*9][144]
                             const float* __restrict__ ob,   // [144]
                             const float* __restrict__ dwT,  // [16*9][16]
                             const float* __restrict__ db,   // [16]
                             float* __restrict__ o0, float* __restrict__ o1,
                             float* __restrict__ o2) {
    const int s = blockIdx.z >> 2;
    const int b = blockIdx.z & 3;
    const int H = 192 - 2 * s, W = H;
    const float* x    = s == 0 ? x0 : (s == 1 ? x1 : x2);
    const float* offF = s == 0 ? f0 : (s == 1 ? f1 : f2);
    float* out        = s == 0 ? o0 : (s == 1 ? o1 : o2);

    __shared__ float tile[16 * 324];
    const int tid = threadIdx.x;
    const int tx0 = blockIdx.x * 16, ty0 = blockIdx.y * 16;
    const int bx = tx0 - 1, by = ty0 - 1;

    for (int idx = tid; idx < 16 * 324; idx += 256) {
        int ci  = idx / 324;
        int rem = idx - ci * 324;
        int r = rem / 18, c = rem - r * 18;
        int gy = by + r, gx = bx + c;
        float v = 0.f;
        if (gy >= 0 && gy < H && gx >= 0 && gx < W)
            v = offF[((size_t)(b * 16 + ci) * H + gy) * W + gx];
        tile[idx] = v;
    }
    __syncthreads();

    const int ox = tid & 15, oy = tid >> 4;
    const int gy = ty0 + oy, gx = tx0 + ox;
    const int HW = H * W;

    float acc[16];
#pragma unroll
    for (int co = 0; co < 16; ++co) acc[co] = db[co];

#pragma unroll 1
    for (int dg = 0; dg < 8; ++dg) {
        // ---- offsets for this deform group: 18 values (y,x per 9 taps) ----
        float offv[18];
#pragma unroll
        for (int j = 0; j < 18; ++j) offv[j] = ob[dg * 18 + j];

#pragma unroll 1
        for (int ci = 0; ci < 16; ++ci) {
            const float* tc = &tile[ci * 324];
#pragma unroll
            for (int t = 0; t < 9; ++t) {
                float v = tc[(oy + t / 3) * 18 + ox + (t % 3)];
                const float* wrow = &owT[(ci * 9 + t) * 144 + dg * 18];
#pragma unroll
                for (int j = 0; j < 18; ++j) offv[j] += v * wrow[j];
            }
        }

        // ---- bilinear sampling + accumulate into 16 output channels ----
        const float* xb = x + (size_t)(b * 16 + dg * 2) * HW;
#pragma unroll
        for (int k = 0; k < 9; ++k) {
            float sy = (float)(gy + k / 3 - 1) + offv[2 * k];
            float sx = (float)(gx + (k % 3) - 1) + offv[2 * k + 1];
            float fy = floorf(sy), fx = floorf(sx);
            int y0 = (int)fy, x0 = (int)fx;
            float wy = sy - fy, wx = sx - fx;
            bool y0v = (y0 >= 0) && (y0 < H);
            bool y1v = (y0 + 1 >= 0) && (y0 + 1 < H);
            bool x0v = (x0 >= 0) && (x0 < W);
            bool x1v = (x0 + 1 >= 0) && (x0 + 1 < W);
            int i00 = y0 * W + x0;
#pragma unroll
            for (int c2 = 0; c2 < 2; ++c2) {
                const float* p = xb + c2 * HW;
                float v00 = (y0v && x0v) ? p[i00] : 0.f;
                float v01 = (y0v && x1v) ? p[i00 + 1] : 0.f;
                float v10 = (y1v && x0v) ? p[i00 + W] : 0.f;
                float v11 = (y1v && x1v) ? p[i00 + W + 1] : 0.f;
                float top = v00 + (v01 - v00) * wx;
                float bot = v10 + (v11 - v10) * wx;
                float sfin = top + (bot - top) * wy;
                const float* wrow = &dwT[((dg * 2 + c2) * 9 + k) * 16];
#pragma unroll
                for (int co = 0; co < 16; ++co) acc[co] += sfin * wrow[co];
            }
        }
    }

    if (gy < H && gx < W) {
#pragma unroll
        for (int co = 0; co < 16; ++co)
            out[((size_t)(b * 16 + co) * H + gy) * W + gx] = acc[co];
    }
}

// ---------------------------------------------------------------------------
extern "C" void kernel_launch(void* const* d_in, const int* in_sizes, int n_in,
                              void* d_out, int out_size, void* d_ws, size_t ws_size,
                              hipStream_t stream) {
    const float* ref_image = (const float*)d_in[0];
    const float* unreg_image = (const float*)d_in[1];
    const float* fe_w1 = (const float*)d_in[2];
    const float* fe_b1 = (const float*)d_in[3];
    const float* fe_w2 = (const float*)d_in[4];
    const float* fe_b2 = (const float*)d_in[5];
    const float* fe_w3 = (const float*)d_in[6];
    const float* fe_b3 = (const float*)d_in[7];
    const float* off_w0 = (const float*)d_in[8];
    const float* off_b0 = (const float*)d_in[9];
    const float* off_w1 = (const float*)d_in[10];
    const float* off_b1 = (const float*)d_in[11];
    const float* off_w2 = (const float*)d_in[12];
    const float* off_b2 = (const float*)d_in[13];
    const float* dcn_off_w = (const float*)d_in[14];
    const float* dcn_off_b = (const float*)d_in[15];
    const float* dcn_w = (const float*)d_in[16];
    const float* dcn_b = (const float*)d_in[17];

    const int B = 4;
    const size_t sz1 = (size_t)B * 16 * 192 * 192;
    const size_t sz2 = (size_t)B * 16 * 190 * 190;
    const size_t sz3 = (size_t)B * 16 * 188 * 188;

    float* p = (float*)d_ws;
    float* ref_f1 = p; p += sz1;
    float* unr_f1 = p; p += sz1;
    float* ref_f2 = p; p += sz2;
    float* unr_f2 = p; p += sz2;
    float* ref_f3 = p; p += sz3;
    float* unr_f3 = p; p += sz3;
    float* off_feat0 = p; p += sz1;
    float* off_feat1 = p; p += sz2;
    float* off_feat2 = p; p += sz3;
    float* wT_fe1 = p; p += 16 * 16 * 9;
    float* wT_fe2 = p; p += 16 * 16 * 9;
    float* wT_fe3 = p; p += 16 * 16 * 9;
    float* wT_off0 = p; p += 16 * 32 * 9;
    float* wT_off1 = p; p += 16 * 32 * 9;
    float* wT_off2 = p; p += 16 * 32 * 9;
    float* owT = p; p += 144 * 16 * 9;
    float* dwT = p; p += 16 * 16 * 9;

    float* out0 = (float*)d_out;
    float* out1 = out0 + sz1;
    float* out2 = out1 + sz2;

    dim3 blk(256);

    // 1. all weight transposes
    transpose_all_k<<<dim3(81, 8), blk, 0, stream>>>(
        fe_w1, fe_w2, fe_w3, off_w0, off_w1, off_w2, dcn_off_w, dcn_w,
        wT_fe1, wT_fe2, wT_fe3, wT_off0, wT_off1, wT_off2, owT, dwT);

    // 2-4. feature extraction (both images per launch)
    conv_fe_k<true><<<dim3(12, 12, 8), blk, 0, stream>>>(
        ref_image, unreg_image, wT_fe1, fe_b1, ref_f1, unr_f1, 192, 192, 192, 192);
    conv_fe_k<false><<<dim3(12, 12, 8), blk, 0, stream>>>(
        ref_f1, unr_f1, wT_fe2, fe_b2, ref_f2, unr_f2, 192, 192, 190, 190);
    conv_fe_k<false><<<dim3(12, 12, 8), blk, 0, stream>>>(
        ref_f2, unr_f2, wT_fe3, fe_b3, ref_f3, unr_f3, 190, 190, 188, 188);

    // 5. all three offset-feature convs
    conv_off_k<<<dim3(12, 12, 12), blk, 0, stream>>>(
        ref_f1, ref_f2, ref_f3, unr_f1, unr_f2, unr_f3,
        wT_off0, wT_off1, wT_off2, off_b0, off_b1, off_b2,
        off_feat0, off_feat1, off_feat2);

    // 6. all three fused offset-conv + deform convs
    deform_all_k<<<dim3(12, 12, 12), blk, 0, stream>>>(
        unr_f1, unr_f2, unr_f3, off_feat0, off_feat1, off_feat2,
        owT, dcn_off_b, dwT, dcn_b, out0, out1, out2);
}

// Round 3
// 608.165 us; speedup vs baseline: 1.3154x; 1.1147x over previous
//
#include <hip/hip_runtime.h>

typedef unsigned int uint;
typedef unsigned short ushort;
typedef __attribute__((ext_vector_type(8))) short bf16x8;
typedef __attribute__((ext_vector_type(4))) float f32x4;

__device__ inline ushort f2bf(float f) {           // f32 -> bf16 RNE
    uint u = __float_as_uint(f);
    u += 0x7fff + ((u >> 16) & 1);
    return (ushort)(u >> 16);
}
__device__ inline float bflo(uint w) { return __uint_as_float(w << 16); }
__device__ inline float bfhi(uint w) { return __uint_as_float(w & 0xffff0000u); }

// ---------------- weight transposes: [16][Cin][9] -> [Cin*9][16] ------------
__global__ void transpose_all_k(
    const float* __restrict__ fe_w1, const float* __restrict__ fe_w2,
    const float* __restrict__ fe_w3, const float* __restrict__ off_w0,
    const float* __restrict__ off_w1, const float* __restrict__ off_w2,
    const float* __restrict__ dcn_w,
    float* __restrict__ wT1, float* __restrict__ wT2, float* __restrict__ wT3,
    float* __restrict__ wTo0, float* __restrict__ wTo1, float* __restrict__ wTo2,
    float* __restrict__ dwT) {
    const float* w; float* wT; int Cin;
    switch (blockIdx.y) {
        case 0: w = fe_w1; wT = wT1; Cin = 16; break;
        case 1: w = fe_w2; wT = wT2; Cin = 16; break;
        case 2: w = fe_w3; wT = wT3; Cin = 16; break;
        case 3: w = off_w0; wT = wTo0; Cin = 32; break;
        case 4: w = off_w1; wT = wTo1; Cin = 32; break;
        case 5: w = off_w2; wT = wTo2; Cin = 32; break;
        default: w = dcn_w; wT = dwT; Cin = 16; break;
    }
    int idx = blockIdx.x * 256 + threadIdx.x;
    if (idx >= 16 * Cin * 9) return;
    int t  = idx % 9;
    int ci = (idx / 9) % Cin;
    int co = idx / (9 * Cin);
    wT[(ci * 9 + t) * 16 + co] = w[idx];
}

// ---- pack dcn_off_w [144][16][3][3] into MFMA B-fragment order, bf16 -------
// k-order: k = tap*16 + ci, K padded 144->160 (tap 9 = zeros).
// frag elem (kstep, ntile, lane, e): k = kstep*32 + (lane>>4)*8 + e,
//                                    n = ntile*16 + (lane&15)
__global__ void pack_ow_k(const float* __restrict__ w, ushort* __restrict__ pack) {
    int i = blockIdx.x * 256 + threadIdx.x;     // 5*9*64*8 = 23040
    if (i >= 23040) return;
    int e    = i & 7;
    int lane = (i >> 3) & 63;
    int rest = i >> 9;
    int nt   = rest % 9;
    int ks   = rest / 9;
    int k = ks * 32 + (lane >> 4) * 8 + e;
    int n = nt * 16 + (lane & 15);
    int t = k >> 4, ci = k & 15;
    float v = (t < 9) ? w[(n * 16 + ci) * 9 + t] : 0.f;
    pack[i] = f2bf(v);
}

// ---------------- FE conv: CIN=16, both images in one launch ----------------
template <bool PAD1>
__launch_bounds__(256)
__global__ void conv_fe_k(const float* __restrict__ inA, const float* __restrict__ inB,
                          const float* __restrict__ wT, const float* __restrict__ bias,
                          float* __restrict__ outA, float* __restrict__ outB,
                          int H, int W, int OH, int OW) {
    __shared__ float tile[16 * 324];
    const int tid = threadIdx.x;
    const int tx0 = blockIdx.x * 16, ty0 = blockIdx.y * 16;
    const int b = blockIdx.z & 3;
    const int img = blockIdx.z >> 2;
    const float* in = img ? inB : inA;
    float* out = img ? outB : outA;
    const int bx = tx0 - (PAD1 ? 1 : 0), by = ty0 - (PAD1 ? 1 : 0);

    for (int idx = tid; idx < 16 * 324; idx += 256) {
        int ci  = idx / 324;
        int rem = idx - ci * 324;
        int r = rem / 18, c = rem - r * 18;
        int gy = by + r, gx = bx + c;
        float v = 0.f;
        if (gy >= 0 && gy < H && gx >= 0 && gx < W)
            v = in[((size_t)(b * 16 + ci) * H + gy) * W + gx];
        tile[idx] = v;
    }
    __syncthreads();

    const int ox = tid & 15, oy = tid >> 4;
    float acc[16];
#pragma unroll
    for (int co = 0; co < 16; ++co) acc[co] = bias[co];

#pragma unroll 1
    for (int ci = 0; ci < 16; ++ci) {
        const float* tc = &tile[ci * 324];
#pragma unroll
        for (int t = 0; t < 9; ++t) {
            float v = tc[(oy + t / 3) * 18 + ox + (t % 3)];
            const float* wrow = &wT[(ci * 9 + t) * 16];
#pragma unroll
            for (int co = 0; co < 16; ++co) acc[co] += v * wrow[co];
        }
    }

    const int gy = ty0 + oy, gx = tx0 + ox;
    if (gy < OH && gx < OW) {
#pragma unroll
        for (int co = 0; co < 16; ++co)
            out[((size_t)(b * 16 + co) * OH + gy) * OW + gx] = fmaxf(acc[co], 0.f);
    }
}

// ------- offset-feature conv (CIN=32), writes bf16 channel-last [pix][16] ---
__launch_bounds__(256)
__global__ void conv_off_k(const float* __restrict__ r0, const float* __restrict__ r1,
                           const float* __restrict__ r2, const float* __restrict__ u0,
                           const float* __restrict__ u1, const float* __restrict__ u2,
                           const float* __restrict__ w0, const float* __restrict__ w1,
                           const float* __restrict__ w2, const float* __restrict__ b0,
                           const float* __restrict__ b1, const float* __restrict__ b2,
                           ushort* __restrict__ f0, ushort* __restrict__ f1,
                           ushort* __restrict__ f2) {
    const int s = blockIdx.z >> 2;
    const int b = blockIdx.z & 3;
    const int H = 192 - 2 * s, W = H;
    const float* inR  = s == 0 ? r0 : (s == 1 ? r1 : r2);
    const float* inU  = s == 0 ? u0 : (s == 1 ? u1 : u2);
    const float* wT   = s == 0 ? w0 : (s == 1 ? w1 : w2);
    const float* bias = s == 0 ? b0 : (s == 1 ? b1 : b2);
    ushort* out       = s == 0 ? f0 : (s == 1 ? f1 : f2);

    __shared__ float tile[16 * 324];
    const int tid = threadIdx.x;
    const int tx0 = blockIdx.x * 16, ty0 = blockIdx.y * 16;
    const int bx = tx0 - 1, by = ty0 - 1;
    const int ox = tid & 15, oy = tid >> 4;

    float acc[16];
#pragma unroll
    for (int co = 0; co < 16; ++co) acc[co] = bias[co];

#pragma unroll 1
    for (int chunk = 0; chunk < 2; ++chunk) {
        const float* in = chunk ? inU : inR;
        if (chunk) __syncthreads();
        for (int idx = tid; idx < 16 * 324; idx += 256) {
            int ci  = idx / 324;
            int rem = idx - ci * 324;
            int r = rem / 18, c = rem - r * 18;
            int gy = by + r, gx = bx + c;
            float v = 0.f;
            if (gy >= 0 && gy < H && gx >= 0 && gx < W)
                v = in[((size_t)(b * 16 + ci) * H + gy) * W + gx];
            tile[idx] = v;
        }
        __syncthreads();

#pragma unroll 1
        for (int ci = 0; ci < 16; ++ci) {
            const float* tc = &tile[ci * 324];
#pragma unroll
            for (int t = 0; t < 9; ++t) {
                float v = tc[(oy + t / 3) * 18 + ox + (t % 3)];
                const float* wrow = &wT[((chunk * 16 + ci) * 9 + t) * 16];
#pragma unroll
                for (int co = 0; co < 16; ++co) acc[co] += v * wrow[co];
            }
        }
    }

    const int gy = ty0 + oy, gx = tx0 + ox;
    if (gy < H && gx < W) {
        size_t pixi = (size_t)(b * H + gy) * W + gx;
        uint o16[8];
#pragma unroll
        for (int i = 0; i < 8; ++i) {
            uint lo = f2bf(fmaxf(acc[2 * i], 0.f));
            uint hi = f2bf(fmaxf(acc[2 * i + 1], 0.f));
            o16[i] = lo | (hi << 16);
        }
        uint4* dst = (uint4*)(out + pixi * 16);
        dst[0] = *(uint4*)&o16[0];
        dst[1] = *(uint4*)&o16[4];
    }
}

// ------------- MFMA offset conv: off_feat bf16 -> offsets bf16 [pix][144] ---
__launch_bounds__(256)
__global__ void offconv_mfma_k(const ushort* __restrict__ fb0, const ushort* __restrict__ fb1,
                               const ushort* __restrict__ fb2,
                               const ushort* __restrict__ owPack, const float* __restrict__ ob,
                               ushort* __restrict__ of0, ushort* __restrict__ of1,
                               ushort* __restrict__ of2, int zbase) {
    const int z = blockIdx.z + zbase;
    const int s = z >> 2, b = z & 3;
    const int H = 192 - 2 * s, W = H;
    const ushort* fb = s == 0 ? fb0 : (s == 1 ? fb1 : fb2);
    ushort* ofs = s == 0 ? of0 : (s == 1 ? of1 : of2);

    __shared__ ushort patch[324 * 16];   // [pos(18x18)][ci] bf16, 10.1 KB
    const int tid = threadIdx.x;
    const int tx0 = blockIdx.x * 16, ty0 = blockIdx.y * 16;

    for (int c = tid; c < 648; c += 256) {       // 648 x 16B chunks
        int pos = c >> 1, h = c & 1;
        int r = pos / 18, col = pos - r * 18;
        int gy = ty0 - 1 + r, gx = tx0 - 1 + col;
        uint4 v = make_uint4(0, 0, 0, 0);
        if (gy >= 0 && gy < H && gx >= 0 && gx < W)
            v = *(const uint4*)(fb + ((size_t)(b * H + gy) * W + gx) * 16 + h * 8);
        *(uint4*)(patch + pos * 16 + h * 8) = v;
    }
    __syncthreads();

    const int lane = tid & 63, wv = tid >> 6;
    const int g = lane >> 4, ci0 = (g & 1) * 8, rowx = lane & 15;

    f32x4 acc[4][9];
#pragma unroll
    for (int n = 0; n < 9; ++n) {
        float bv = ob[n * 16 + rowx];
#pragma unroll
        for (int m = 0; m < 4; ++m) acc[m][n] = f32x4{bv, bv, bv, bv};
    }

#pragma unroll
    for (int ks = 0; ks < 5; ++ks) {
        int t = 2 * ks + (g >> 1);               // tap for this lane group
        int dy = t < 9 ? t / 3 : 0;
        int dx = t < 9 ? t - (t / 3) * 3 : 0;
        bf16x8 a[4];
#pragma unroll
        for (int m = 0; m < 4; ++m) {
            int r = wv * 4 + m + dy, cc = rowx + dx;
            a[m] = *(const bf16x8*)(patch + (r * 18 + cc) * 16 + ci0);
        }
        const uint4* bp = (const uint4*)owPack + (size_t)(ks * 9) * 64 + lane;
#pragma unroll
        for (int n = 0; n < 9; ++n) {
            bf16x8 bfrag = *(const bf16x8*)(bp + (size_t)n * 64);
#pragma unroll
            for (int m = 0; m < 4; ++m)
                acc[m][n] = __builtin_amdgcn_mfma_f32_16x16x32_bf16(a[m], bfrag, acc[m][n], 0, 0, 0);
        }
    }

    const int oxb = (lane >> 4) * 4;
#pragma unroll
    for (int m = 0; m < 4; ++m) {
        int gy = ty0 + wv * 4 + m;
        if (gy >= H) continue;
#pragma unroll
        for (int n = 0; n < 9; ++n) {
            int ch = n * 16 + rowx;
#pragma unroll
            for (int j = 0; j < 4; ++j) {
                int gx = tx0 + oxb + j;
                if (gx < W)
                    ofs[((size_t)(b * H + gy) * W + gx) * 144 + ch] = f2bf(acc[m][n][j]);
            }
        }
    }
}

// ---------------- bilinear sampling + 16-ch deform conv accumulate ----------
__launch_bounds__(256)
__global__ void sample_k(const float* __restrict__ x0, const float* __restrict__ x1,
                         const float* __restrict__ x2,
                         const ushort* __restrict__ of0, const ushort* __restrict__ of1,
                         const ushort* __restrict__ of2,
                         const float* __restrict__ dwT, const float* __restrict__ db,
                         float* __restrict__ o0, float* __restrict__ o1,
                         float* __restrict__ o2, int zbase) {
    const int z = blockIdx.z + zbase;
    const int s = z >> 2, b = z & 3;
    const int H = 192 - 2 * s, W = H;
    const float* x = s == 0 ? x0 : (s == 1 ? x1 : x2);
    const ushort* ofs = s == 0 ? of0 : (s == 1 ? of1 : of2);
    float* out = s == 0 ? o0 : (s == 1 ? o1 : o2);

    const int tid = threadIdx.x;
    const int gx = blockIdx.x * 16 + (tid & 15);
    const int gy = blockIdx.y * 16 + (tid >> 4);
    if (gy >= H || gx >= W) return;
    const int HW = H * W;

    uint off[72];
    const uint* op = (const uint*)(ofs + ((size_t)(b * H + gy) * W + gx) * 144);
#pragma unroll
    for (int i = 0; i < 72; ++i) off[i] = op[i];

    float acc[16];
#pragma unroll
    for (int co = 0; co < 16; ++co) acc[co] = db[co];

    const float* xb = x + (size_t)(b * 16) * HW;
#pragma unroll
    for (int dg = 0; dg < 8; ++dg) {
        const float* p0 = xb + (size_t)(2 * dg) * HW;
        const float* p1 = p0 + HW;
#pragma unroll
        for (int k = 0; k < 9; ++k) {
            uint wo = off[dg * 9 + k];
            float sy = (float)(gy + k / 3 - 1) + bflo(wo);
            float sx = (float)(gx + k % 3 - 1) + bfhi(wo);
            float fy = floorf(sy), fx = floorf(sx);
            int y0 = (int)fy, x0i = (int)fx;
            float wy = sy - fy, wx = sx - fx;
            bool y0v = (y0 >= 0) && (y0 < H);
            bool y1v = (y0 + 1 >= 0) && (y0 + 1 < H);
            bool x0v = (x0i >= 0) && (x0i < W);
            bool x1v = (x0i + 1 >= 0) && (x0i + 1 < W);
            int i00 = y0 * W + x0i;
            float w00 = (1.f - wy) * (1.f - wx), w01 = (1.f - wy) * wx;
            float w10 = wy * (1.f - wx), w11 = wy * wx;
            float s0 = 0.f, s1 = 0.f;
            if (y0v && x0v) { s0 += p0[i00] * w00;         s1 += p1[i00] * w00; }
            if (y0v && x1v) { s0 += p0[i00 + 1] * w01;     s1 += p1[i00 + 1] * w01; }
            if (y1v && x0v) { s0 += p0[i00 + W] * w10;     s1 += p1[i00 + W] * w10; }
            if (y1v && x1v) { s0 += p0[i00 + W + 1] * w11; s1 += p1[i00 + W + 1] * w11; }
            const float* wr0 = dwT + ((size_t)(2 * dg) * 9 + k) * 16;
            const float* wr1 = wr0 + 144;
#pragma unroll
            for (int co = 0; co < 16; ++co) acc[co] += s0 * wr0[co] + s1 * wr1[co];
        }
    }
#pragma unroll
    for (int co = 0; co < 16; ++co)
        out[((size_t)(b * 16 + co) * H + gy) * W + gx] = acc[co];
}

// ---------------------------------------------------------------------------
extern "C" void kernel_launch(void* const* d_in, const int* in_sizes, int n_in,
                              void* d_out, int out_size, void* d_ws, size_t ws_size,
                              hipStream_t stream) {
    const float* ref_image = (const float*)d_in[0];
    const float* unreg_image = (const float*)d_in[1];
    const float* fe_w1 = (const float*)d_in[2];
    const float* fe_b1 = (const float*)d_in[3];
    const float* fe_w2 = (const float*)d_in[4];
    const float* fe_b2 = (const float*)d_in[5];
    const float* fe_w3 = (const float*)d_in[6];
    const float* fe_b3 = (const float*)d_in[7];
    const float* off_w0 = (const float*)d_in[8];
    const float* off_b0 = (const float*)d_in[9];
    const float* off_w1 = (const float*)d_in[10];
    const float* off_b1 = (const float*)d_in[11];
    const float* off_w2 = (const float*)d_in[12];
    const float* off_b2 = (const float*)d_in[13];
    const float* dcn_off_w = (const float*)d_in[14];
    const float* dcn_off_b = (const float*)d_in[15];
    const float* dcn_w = (const float*)d_in[16];
    const float* dcn_b = (const float*)d_in[17];

    const size_t szf[3] = {4ul * 16 * 192 * 192, 4ul * 16 * 190 * 190, 4ul * 16 * 188 * 188};
    const size_t pix[3] = {4ul * 192 * 192, 4ul * 190 * 190, 4ul * 188 * 188};

    size_t o = 0;
    auto take = [&](size_t bytes) {
        void* r = (char*)d_ws + o;
        o += (bytes + 255) & ~(size_t)255;
        return r;
    };
    float* unr[3]; float* ref[3]; ushort* fb[3];
    float* wTfe[3]; float* wToff[3]; float* dwT; ushort* owPack;
    for (int s = 0; s < 3; ++s) unr[s] = (float*)take(szf[s] * 4);
    for (int s = 0; s < 3; ++s) fb[s] = (ushort*)take(pix[s] * 16 * 2);
    for (int s = 0; s < 3; ++s) wTfe[s] = (float*)take(2304 * 4);
    for (int s = 0; s < 3; ++s) wToff[s] = (float*)take(4608 * 4);
    dwT = (float*)take(2304 * 4);
    owPack = (ushort*)take(23040 * 2);
    size_t refStart = o;
    for (int s = 0; s < 3; ++s) ref[s] = (float*)take(szf[s] * 4);
    size_t afterRef = o;

    // offsets buffers: batched (3 bufs) if ws allows, else one reused buffer
    // overlaid on the ref-feature block (ref is dead once conv_off_k ran).
    ushort* offsBuf[3];
    size_t offsB[3] = {pix[0] * 288, pix[1] * 288, pix[2] * 288};
    size_t batchedNeed = afterRef;
    for (int s = 0; s < 3; ++s) batchedNeed += (offsB[s] + 255) & ~(size_t)255;
    bool batched = (ws_size >= batchedNeed);
    if (batched) {
        for (int s = 0; s < 3; ++s) offsBuf[s] = (ushort*)take(offsB[s]);
    } else {
        ushort* one = (ushort*)((char*)d_ws + refStart);
        offsBuf[0] = offsBuf[1] = offsBuf[2] = one;
    }

    float* out0 = (float*)d_out;
    float* out1 = out0 + szf[0];
    float* out2 = out1 + szf[1];

    dim3 blk(256);

    transpose_all_k<<<dim3(18, 7), blk, 0, stream>>>(
        fe_w1, fe_w2, fe_w3, off_w0, off_w1, off_w2, dcn_w,
        wTfe[0], wTfe[1], wTfe[2], wToff[0], wToff[1], wToff[2], dwT);
    pack_ow_k<<<dim3(90), blk, 0, stream>>>(dcn_off_w, owPack);

    conv_fe_k<true><<<dim3(12, 12, 8), blk, 0, stream>>>(
        ref_image, unreg_image, wTfe[0], fe_b1, ref[0], unr[0], 192, 192, 192, 192);
    conv_fe_k<false><<<dim3(12, 12, 8), blk, 0, stream>>>(
        ref[0], unr[0], wTfe[1], fe_b2, ref[1], unr[1], 192, 192, 190, 190);
    conv_fe_k<false><<<dim3(12, 12, 8), blk, 0, stream>>>(
        ref[1], unr[1], wTfe[2], fe_b3, ref[2], unr[2], 190, 190, 188, 188);

    conv_off_k<<<dim3(12, 12, 12), blk, 0, stream>>>(
        ref[0], ref[1], ref[2], unr[0], unr[1], unr[2],
        wToff[0], wToff[1], wToff[2], off_b0, off_b1, off_b2,
        fb[0], fb[1], fb[2]);

    if (batched) {
        offconv_mfma_k<<<dim3(12, 12, 12), blk, 0, stream>>>(
            fb[0], fb[1], fb[2], owPack, dcn_off_b,
            offsBuf[0], offsBuf[1], offsBuf[2], 0);
        sample_k<<<dim3(12, 12, 12), blk, 0, stream>>>(
            unr[0], unr[1], unr[2], offsBuf[0], offsBuf[1], offsBuf[2],
            dwT, dcn_b, out0, out1, out2, 0);
    } else {
        for (int s = 0; s < 3; ++s) {
            offconv_mfma_k<<<dim3(12, 12, 4), blk, 0, stream>>>(
                fb[0], fb[1], fb[2], owPack, dcn_off_b,
                offsBuf[0], offsBuf[1], offsBuf[2], 4 * s);
            sample_k<<<dim3(12, 12, 4), blk, 0, stream>>>(
                unr[0], unr[1], unr[2], offsBuf[0], offsBuf[1], offsBuf[2],
                dwT, dcn_b, out0, out1, out2, 4 * s);
        }
    }
}

// Round 4
// 425.895 us; speedup vs baseline: 1.8784x; 1.4280x over previous
//
#include <hip/hip_runtime.h>

typedef unsigned int uint;
typedef unsigned short ushort;
typedef __attribute__((ext_vector_type(8))) short bf16x8;
typedef __attribute__((ext_vector_type(4))) float f32x4;

__device__ inline ushort f2bf(float f) {           // f32 -> bf16 RNE
    uint u = __float_as_uint(f);
    u += 0x7fff + ((u >> 16) & 1);
    return (ushort)(u >> 16);
}
__device__ inline float bflo(uint w) { return __uint_as_float(w << 16); }
__device__ inline float bfhi(uint w) { return __uint_as_float(w & 0xffff0000u); }

// ---------------- weight transposes: [16][Cin][9] -> [Cin*9][16] ------------
__global__ void transpose_all_k(
    const float* __restrict__ fe_w1, const float* __restrict__ fe_w2,
    const float* __restrict__ fe_w3, const float* __restrict__ off_w0,
    const float* __restrict__ off_w1, const float* __restrict__ off_w2,
    const float* __restrict__ dcn_w,
    float* __restrict__ wT1, float* __restrict__ wT2, float* __restrict__ wT3,
    float* __restrict__ wTo0, float* __restrict__ wTo1, float* __restrict__ wTo2,
    float* __restrict__ dwT) {
    const float* w; float* wT; int Cin;
    switch (blockIdx.y) {
        case 0: w = fe_w1; wT = wT1; Cin = 16; break;
        case 1: w = fe_w2; wT = wT2; Cin = 16; break;
        case 2: w = fe_w3; wT = wT3; Cin = 16; break;
        case 3: w = off_w0; wT = wTo0; Cin = 32; break;
        case 4: w = off_w1; wT = wTo1; Cin = 32; break;
        case 5: w = off_w2; wT = wTo2; Cin = 32; break;
        default: w = dcn_w; wT = dwT; Cin = 16; break;
    }
    int idx = blockIdx.x * 256 + threadIdx.x;
    if (idx >= 16 * Cin * 9) return;
    int t  = idx % 9;
    int ci = (idx / 9) % Cin;
    int co = idx / (9 * Cin);
    wT[(ci * 9 + t) * 16 + co] = w[idx];
}

// ---- pack dcn_off_w [144][16][3][3] into MFMA B-fragment order, bf16 -------
__global__ void pack_ow_k(const float* __restrict__ w, ushort* __restrict__ pack) {
    int i = blockIdx.x * 256 + threadIdx.x;     // 5*9*64*8 = 23040
    if (i >= 23040) return;
    int e    = i & 7;
    int lane = (i >> 3) & 63;
    int rest = i >> 9;
    int nt   = rest % 9;
    int ks   = rest / 9;
    int k = ks * 32 + (lane >> 4) * 8 + e;
    int n = nt * 16 + (lane & 15);
    int t = k >> 4, ci = k & 15;
    float v = (t < 9) ? w[(n * 16 + ci) * 9 + t] : 0.f;
    pack[i] = f2bf(v);
}

// ---------------- FE conv: CIN=16, both images in one launch ----------------
template <bool PAD1>
__launch_bounds__(256)
__global__ void conv_fe_k(const float* __restrict__ inA, const float* __restrict__ inB,
                          const float* __restrict__ wT, const float* __restrict__ bias,
                          float* __restrict__ outA, float* __restrict__ outB,
                          int H, int W, int OH, int OW) {
    __shared__ float tile[16 * 324];
    const int tid = threadIdx.x;
    const int tx0 = blockIdx.x * 16, ty0 = blockIdx.y * 16;
    const int b = blockIdx.z & 3;
    const int img = blockIdx.z >> 2;
    const float* in = img ? inB : inA;
    float* out = img ? outB : outA;
    const int bx = tx0 - (PAD1 ? 1 : 0), by = ty0 - (PAD1 ? 1 : 0);

    for (int idx = tid; idx < 16 * 324; idx += 256) {
        int ci  = idx / 324;
        int rem = idx - ci * 324;
        int r = rem / 18, c = rem - r * 18;
        int gy = by + r, gx = bx + c;
        float v = 0.f;
        if (gy >= 0 && gy < H && gx >= 0 && gx < W)
            v = in[((size_t)(b * 16 + ci) * H + gy) * W + gx];
        tile[idx] = v;
    }
    __syncthreads();

    const int ox = tid & 15, oy = tid >> 4;
    float acc[16];
#pragma unroll
    for (int co = 0; co < 16; ++co) acc[co] = bias[co];

#pragma unroll 1
    for (int ci = 0; ci < 16; ++ci) {
        const float* tc = &tile[ci * 324];
#pragma unroll
        for (int t = 0; t < 9; ++t) {
            float v = tc[(oy + t / 3) * 18 + ox + (t % 3)];
            const float* wrow = &wT[(ci * 9 + t) * 16];
#pragma unroll
            for (int co = 0; co < 16; ++co) acc[co] += v * wrow[co];
        }
    }

    const int gy = ty0 + oy, gx = tx0 + ox;
    if (gy < OH && gx < OW) {
#pragma unroll
        for (int co = 0; co < 16; ++co)
            out[((size_t)(b * 16 + co) * OH + gy) * OW + gx] = fmaxf(acc[co], 0.f);
    }
}

// ------- offset-feature conv (CIN=32), writes bf16 channel-last [pix][16] ---
__launch_bounds__(256)
__global__ void conv_off_k(const float* __restrict__ r0, const float* __restrict__ r1,
                           const float* __restrict__ r2, const float* __restrict__ u0,
                           const float* __restrict__ u1, const float* __restrict__ u2,
                           const float* __restrict__ w0, const float* __restrict__ w1,
                           const float* __restrict__ w2, const float* __restrict__ b0,
                           const float* __restrict__ b1, const float* __restrict__ b2,
                           ushort* __restrict__ f0, ushort* __restrict__ f1,
                           ushort* __restrict__ f2) {
    const int s = blockIdx.z >> 2;
    const int b = blockIdx.z & 3;
    const int H = 192 - 2 * s, W = H;
    const float* inR  = s == 0 ? r0 : (s == 1 ? r1 : r2);
    const float* inU  = s == 0 ? u0 : (s == 1 ? u1 : u2);
    const float* wT   = s == 0 ? w0 : (s == 1 ? w1 : w2);
    const float* bias = s == 0 ? b0 : (s == 1 ? b1 : b2);
    ushort* out       = s == 0 ? f0 : (s == 1 ? f1 : f2);

    __shared__ float tile[16 * 324];
    const int tid = threadIdx.x;
    const int tx0 = blockIdx.x * 16, ty0 = blockIdx.y * 16;
    const int bx = tx0 - 1, by = ty0 - 1;
    const int ox = tid & 15, oy = tid >> 4;

    float acc[16];
#pragma unroll
    for (int co = 0; co < 16; ++co) acc[co] = bias[co];

#pragma unroll 1
    for (int chunk = 0; chunk < 2; ++chunk) {
        const float* in = chunk ? inU : inR;
        if (chunk) __syncthreads();
        for (int idx = tid; idx < 16 * 324; idx += 256) {
            int ci  = idx / 324;
            int rem = idx - ci * 324;
            int r = rem / 18, c = rem - r * 18;
            int gy = by + r, gx = bx + c;
            float v = 0.f;
            if (gy >= 0 && gy < H && gx >= 0 && gx < W)
                v = in[((size_t)(b * 16 + ci) * H + gy) * W + gx];
            tile[idx] = v;
        }
        __syncthreads();

#pragma unroll 1
        for (int ci = 0; ci < 16; ++ci) {
            const float* tc = &tile[ci * 324];
#pragma unroll
            for (int t = 0; t < 9; ++t) {
                float v = tc[(oy + t / 3) * 18 + ox + (t % 3)];
                const float* wrow = &wT[((chunk * 16 + ci) * 9 + t) * 16];
#pragma unroll
                for (int co = 0; co < 16; ++co) acc[co] += v * wrow[co];
            }
        }
    }

    const int gy = ty0 + oy, gx = tx0 + ox;
    if (gy < H && gx < W) {
        size_t pixi = (size_t)(b * H + gy) * W + gx;
        uint o16[8];
#pragma unroll
        for (int i = 0; i < 8; ++i) {
            uint lo = f2bf(fmaxf(acc[2 * i], 0.f));
            uint hi = f2bf(fmaxf(acc[2 * i + 1], 0.f));
            o16[i] = lo | (hi << 16);
        }
        uint4* dst = (uint4*)(out + pixi * 16);
        dst[0] = *(uint4*)&o16[0];
        dst[1] = *(uint4*)&o16[4];
    }
}

// ------------- MFMA offset conv: off_feat bf16 -> offsets bf16 --------------
// output layout: [pix][160] bf16, dg-padded: value (dg, j) at pix*160 + dg*20 + j
__launch_bounds__(256)
__global__ void offconv_mfma_k(const ushort* __restrict__ fb0, const ushort* __restrict__ fb1,
                               const ushort* __restrict__ fb2,
                               const ushort* __restrict__ owPack, const float* __restrict__ ob,
                               ushort* __restrict__ of0, ushort* __restrict__ of1,
                               ushort* __restrict__ of2, int zbase) {
    const int z = blockIdx.z + zbase;
    const int s = z >> 2, b = z & 3;
    const int H = 192 - 2 * s, W = H;
    const ushort* fb = s == 0 ? fb0 : (s == 1 ? fb1 : fb2);
    ushort* ofs = s == 0 ? of0 : (s == 1 ? of1 : of2);

    __shared__ ushort patch[324 * 16];   // [pos(18x18)][ci] bf16, 10.1 KB
    const int tid = threadIdx.x;
    const int tx0 = blockIdx.x * 16, ty0 = blockIdx.y * 16;

    for (int c = tid; c < 648; c += 256) {       // 648 x 16B chunks
        int pos = c >> 1, h = c & 1;
        int r = pos / 18, col = pos - r * 18;
        int gy = ty0 - 1 + r, gx = tx0 - 1 + col;
        uint4 v = make_uint4(0, 0, 0, 0);
        if (gy >= 0 && gy < H && gx >= 0 && gx < W)
            v = *(const uint4*)(fb + ((size_t)(b * H + gy) * W + gx) * 16 + h * 8);
        *(uint4*)(patch + pos * 16 + h * 8) = v;
    }
    __syncthreads();

    const int lane = tid & 63, wv = tid >> 6;
    const int g = lane >> 4, ci0 = (g & 1) * 8, rowx = lane & 15;

    f32x4 acc[4][9];
#pragma unroll
    for (int n = 0; n < 9; ++n) {
        float bv = ob[n * 16 + rowx];
#pragma unroll
        for (int m = 0; m < 4; ++m) acc[m][n] = f32x4{bv, bv, bv, bv};
    }

#pragma unroll
    for (int ks = 0; ks < 5; ++ks) {
        int t = 2 * ks + (g >> 1);               // tap for this lane group
        int dy = t < 9 ? t / 3 : 0;
        int dx = t < 9 ? t - (t / 3) * 3 : 0;
        bf16x8 a[4];
#pragma unroll
        for (int m = 0; m < 4; ++m) {
            int r = wv * 4 + m + dy, cc = rowx + dx;
            a[m] = *(const bf16x8*)(patch + (r * 18 + cc) * 16 + ci0);
        }
        const uint4* bp = (const uint4*)owPack + (size_t)(ks * 9) * 64 + lane;
#pragma unroll
        for (int n = 0; n < 9; ++n) {
            bf16x8 bfrag = *(const bf16x8*)(bp + (size_t)n * 64);
#pragma unroll
            for (int m = 0; m < 4; ++m)
                acc[m][n] = __builtin_amdgcn_mfma_f32_16x16x32_bf16(a[m], bfrag, acc[m][n], 0, 0, 0);
        }
    }

    const int oxb = (lane >> 4) * 4;
#pragma unroll
    for (int n = 0; n < 9; ++n) {
        int ch = n * 16 + rowx;                  // 0..143
        int dgq = ch / 18;
        int col20 = dgq * 20 + (ch - dgq * 18);
#pragma unroll
        for (int m = 0; m < 4; ++m) {
            int gy = ty0 + wv * 4 + m;
            if (gy >= H) continue;
#pragma unroll
            for (int j = 0; j < 4; ++j) {
                int gx = tx0 + oxb + j;
                if (gx < W)
                    ofs[((size_t)(b * H + gy) * W + gx) * 160 + col20] = f2bf(acc[m][n][j]);
            }
        }
    }
}

// ---------------- bilinear sampling + 16-ch deform conv accumulate ----------
// x tile staged in LDS (halo 3); global fallback for out-of-tile samples.
__launch_bounds__(256)
__global__ void sample_k(const float* __restrict__ x0, const float* __restrict__ x1,
                         const float* __restrict__ x2,
                         const ushort* __restrict__ of0, const ushort* __restrict__ of1,
                         const ushort* __restrict__ of2,
                         const float* __restrict__ dwT, const float* __restrict__ db,
                         float* __restrict__ o0, float* __restrict__ o1,
                         float* __restrict__ o2, int zbase) {
    const int z = blockIdx.z + zbase;
    const int s = z >> 2, b = z & 3;
    const int H = 192 - 2 * s, W = H;
    const float* x = s == 0 ? x0 : (s == 1 ? x1 : x2);
    const ushort* ofs = s == 0 ? of0 : (s == 1 ? of1 : of2);
    float* out = s == 0 ? o0 : (s == 1 ? o1 : o2);
    const int HW = H * W;
    const float* xb = x + (size_t)(b * 16) * HW;

    __shared__ float2 xt[8][22 * 22];            // [ch pair][pos], 31 KB
    const int tid = threadIdx.x;
    const int tx0 = blockIdx.x * 16, ty0 = blockIdx.y * 16;
    const int bx = tx0 - 3, by = ty0 - 3;

    // ---- stage x tile (zeros outside image -> zero-pad for free) ----
#pragma unroll 1
    for (int ci = 0; ci < 16; ++ci) {
        const float* pc = xb + (size_t)ci * HW;
        float* dst = (float*)&xt[ci >> 1][0] + (ci & 1);
#pragma unroll 1
        for (int pos = tid; pos < 484; pos += 256) {
            int r = pos / 22, c = pos - r * 22;
            int gy2 = by + r, gx2 = bx + c;
            float v = 0.f;
            if ((unsigned)gy2 < (unsigned)H && (unsigned)gx2 < (unsigned)W)
                v = pc[gy2 * W + gx2];
            dst[pos * 2] = v;
        }
    }
    __syncthreads();

    const int ox = tid & 15, oy = tid >> 4;
    const int gx = tx0 + ox, gy = ty0 + oy;
    const bool live = (gy < H) && (gx < W);
    const int cgy = live ? gy : H - 1, cgx = live ? gx : W - 1;
    const ushort* obase = ofs + ((size_t)(b * H + cgy) * W + cgx) * 160;

    float acc[16];
#pragma unroll
    for (int co = 0; co < 16; ++co) acc[co] = db[co];

#pragma unroll 1
    for (int dg = 0; dg < 8; ++dg) {
        const uint2* op2 = (const uint2*)(obase + dg * 20);
        uint2 q0 = op2[0], q1 = op2[1], q2 = op2[2], q3 = op2[3];
        uint q8 = ((const uint*)op2)[8];
        uint ow[9] = {q0.x, q0.y, q1.x, q1.y, q2.x, q2.y, q3.x, q3.y, q8};
        const float* p0g = xb + (size_t)(2 * dg) * HW;
        const float2* xtd = &xt[dg][0];

#pragma unroll
        for (int k = 0; k < 9; ++k) {
            uint wo = ow[k];
            float sy = (float)(gy + k / 3 - 1) + bflo(wo);
            float sx = (float)(gx + k % 3 - 1) + bfhi(wo);
            float fy = floorf(sy), fx = floorf(sx);
            int y0 = (int)fy, x0i = (int)fx;
            float wy = sy - fy, wx = sx - fx;
            float wy1 = 1.f - wy, wx1 = 1.f - wx;
            float w00 = wy1 * wx1, w01 = wy1 * wx, w10 = wy * wx1, w11 = wy * wx;
            int ly = y0 - by, lx = x0i - bx;
            float2 v00, v01, v10, v11;
            if ((unsigned)ly <= 20u && (unsigned)lx <= 20u) {
                const float2* t = xtd + ly * 22 + lx;
                v00 = t[0]; v01 = t[1]; v10 = t[22]; v11 = t[23];
            } else {
                v00 = v01 = v10 = v11 = make_float2(0.f, 0.f);
                bool y0v = (unsigned)y0 < (unsigned)H;
                bool y1v = (unsigned)(y0 + 1) < (unsigned)H;
                bool x0v = (unsigned)x0i < (unsigned)W;
                bool x1v = (unsigned)(x0i + 1) < (unsigned)W;
                const float* p1g = p0g + HW;
                int i00 = y0 * W + x0i;
                if (y0v && x0v) { v00.x = p0g[i00];         v00.y = p1g[i00]; }
                if (y0v && x1v) { v01.x = p0g[i00 + 1];     v01.y = p1g[i00 + 1]; }
                if (y1v && x0v) { v10.x = p0g[i00 + W];     v10.y = p1g[i00 + W]; }
                if (y1v && x1v) { v11.x = p0g[i00 + W + 1]; v11.y = p1g[i00 + W + 1]; }
            }
            float s0 = w00 * v00.x + w01 * v01.x + w10 * v10.x + w11 * v11.x;
            float s1 = w00 * v00.y + w01 * v01.y + w10 * v10.y + w11 * v11.y;
            const float* wr0 = dwT + ((2 * dg) * 9 + k) * 16;
            const float* wr1 = wr0 + 144;
#pragma unroll
            for (int co = 0; co < 16; ++co) acc[co] += s0 * wr0[co] + s1 * wr1[co];
        }
    }

    if (live) {
#pragma unroll
        for (int co = 0; co < 16; ++co)
            out[((size_t)(b * 16 + co) * H + gy) * W + gx] = acc[co];
    }
}

// ---------------------------------------------------------------------------
extern "C" void kernel_launch(void* const* d_in, const int* in_sizes, int n_in,
                              void* d_out, int out_size, void* d_ws, size_t ws_size,
                              hipStream_t stream) {
    const float* ref_image = (const float*)d_in[0];
    const float* unreg_image = (const float*)d_in[1];
    const float* fe_w1 = (const float*)d_in[2];
    const float* fe_b1 = (const float*)d_in[3];
    const float* fe_w2 = (const float*)d_in[4];
    const float* fe_b2 = (const float*)d_in[5];
    const float* fe_w3 = (const float*)d_in[6];
    const float* fe_b3 = (const float*)d_in[7];
    const float* off_w0 = (const float*)d_in[8];
    const float* off_b0 = (const float*)d_in[9];
    const float* off_w1 = (const float*)d_in[10];
    const float* off_b1 = (const float*)d_in[11];
    const float* off_w2 = (const float*)d_in[12];
    const float* off_b2 = (const float*)d_in[13];
    const float* dcn_off_w = (const float*)d_in[14];
    const float* dcn_off_b = (const float*)d_in[15];
    const float* dcn_w = (const float*)d_in[16];
    const float* dcn_b = (const float*)d_in[17];

    const size_t szf[3] = {4ul * 16 * 192 * 192, 4ul * 16 * 190 * 190, 4ul * 16 * 188 * 188};
    const size_t pix[3] = {4ul * 192 * 192, 4ul * 190 * 190, 4ul * 188 * 188};

    size_t o = 0;
    auto take = [&](size_t bytes) {
        void* r = (char*)d_ws + o;
        o += (bytes + 255) & ~(size_t)255;
        return r;
    };
    float* unr[3]; float* ref[3]; ushort* fb[3];
    float* wTfe[3]; float* wToff[3]; float* dwT; ushort* owPack;
    for (int s = 0; s < 3; ++s) unr[s] = (float*)take(szf[s] * 4);
    for (int s = 0; s < 3; ++s) fb[s] = (ushort*)take(pix[s] * 16 * 2);
    for (int s = 0; s < 3; ++s) wTfe[s] = (float*)take(2304 * 4);
    for (int s = 0; s < 3; ++s) wToff[s] = (float*)take(4608 * 4);
    dwT = (float*)take(2304 * 4);
    owPack = (ushort*)take(23040 * 2);
    size_t refStart = o;
    for (int s = 0; s < 3; ++s) ref[s] = (float*)take(szf[s] * 4);
    size_t afterRef = o;

    // offsets buffers ([pix][160] bf16): batched (3 bufs) if ws allows,
    // else one reused buffer overlaid on the then-dead ref-feature block.
    ushort* offsBuf[3];
    size_t offsB[3] = {pix[0] * 320, pix[1] * 320, pix[2] * 320};
    size_t batchedNeed = afterRef;
    for (int s = 0; s < 3; ++s) batchedNeed += (offsB[s] + 255) & ~(size_t)255;
    bool batched = (ws_size >= batchedNeed);
    if (batched) {
        for (int s = 0; s < 3; ++s) offsBuf[s] = (ushort*)take(offsB[s]);
    } else {
        ushort* one = (ushort*)((char*)d_ws + refStart);
        offsBuf[0] = offsBuf[1] = offsBuf[2] = one;
    }

    float* out0 = (float*)d_out;
    float* out1 = out0 + szf[0];
    float* out2 = out1 + szf[1];

    dim3 blk(256);

    transpose_all_k<<<dim3(18, 7), blk, 0, stream>>>(
        fe_w1, fe_w2, fe_w3, off_w0, off_w1, off_w2, dcn_w,
        wTfe[0], wTfe[1], wTfe[2], wToff[0], wToff[1], wToff[2], dwT);
    pack_ow_k<<<dim3(90), blk, 0, stream>>>(dcn_off_w, owPack);

    conv_fe_k<true><<<dim3(12, 12, 8), blk, 0, stream>>>(
        ref_image, unreg_image, wTfe[0], fe_b1, ref[0], unr[0], 192, 192, 192, 192);
    conv_fe_k<false><<<dim3(12, 12, 8), blk, 0, stream>>>(
        ref[0], unr[0], wTfe[1], fe_b2, ref[1], unr[1], 192, 192, 190, 190);
    conv_fe_k<false><<<dim3(12, 12, 8), blk, 0, stream>>>(
        ref[1], unr[1], wTfe[2], fe_b3, ref[2], unr[2], 190, 190, 188, 188);

    conv_off_k<<<dim3(12, 12, 12), blk, 0, stream>>>(
        ref[0], ref[1], ref[2], unr[0], unr[1], unr[2],
        wToff[0], wToff[1], wToff[2], off_b0, off_b1, off_b2,
        fb[0], fb[1], fb[2]);

    if (batched) {
        offconv_mfma_k<<<dim3(12, 12, 12), blk, 0, stream>>>(
            fb[0], fb[1], fb[2], owPack, dcn_off_b,
            offsBuf[0], offsBuf[1], offsBuf[2], 0);
        sample_k<<<dim3(12, 12, 12), blk, 0, stream>>>(
            unr[0], unr[1], unr[2], offsBuf[0], offsBuf[1], offsBuf[2],
            dwT, dcn_b, out0, out1, out2, 0);
    } else {
        for (int s = 0; s < 3; ++s) {
            offconv_mfma_k<<<dim3(12, 12, 4), blk, 0, stream>>>(
                fb[0], fb[1], fb[2], owPack, dcn_off_b,
                offsBuf[0], offsBuf[1], offsBuf[2], 4 * s);
            sample_k<<<dim3(12, 12, 4), blk, 0, stream>>>(
                unr[0], unr[1], unr[2], offsBuf[0], offsBuf[1], offsBuf[2],
                dwT, dcn_b, out0, out1, out2, 4 * s);
        }
    }
}

// Round 5
// 279.335 us; speedup vs baseline: 2.8639x; 1.5247x over previous
//
#include <hip/hip_runtime.h>

typedef unsigned int uint;
typedef unsigned short ushort;
typedef __attribute__((ext_vector_type(8))) short bf16x8;
typedef __attribute__((ext_vector_type(4))) float f32x4;

__device__ inline ushort f2bf(float f) {           // f32 -> bf16 RNE
    uint u = __float_as_uint(f);
    u += 0x7fff + ((u >> 16) & 1);
    return (ushort)(u >> 16);
}
__device__ inline float bflo(uint w) { return __uint_as_float(w << 16); }
__device__ inline float bfhi(uint w) { return __uint_as_float(w & 0xffff0000u); }

// ---- pack all weights into MFMA B-fragment order (bf16) + dwT transpose ----
// frag linear index i: e=i&7, lane=(i>>3)&63, rest=i>>9, nt=rest%NT, ks=rest/NT
// k = ks*32 + (lane>>4)*8 + e ; n = nt*16 + (lane&15) ; t = k/CIN ; ci = k%CIN
__global__ void packall_k(
    const float* __restrict__ fe_w1, const float* __restrict__ fe_w2,
    const float* __restrict__ fe_w3, const float* __restrict__ off_w0,
    const float* __restrict__ off_w1, const float* __restrict__ off_w2,
    const float* __restrict__ dcn_off_w, const float* __restrict__ dcn_w,
    ushort* __restrict__ pf1, ushort* __restrict__ pf2, ushort* __restrict__ pf3,
    ushort* __restrict__ po0, ushort* __restrict__ po1, ushort* __restrict__ po2,
    ushort* __restrict__ pow_, float* __restrict__ dwT) {
    const int y = blockIdx.y;
    int i = blockIdx.x * 256 + threadIdx.x;
    if (y == 7) {                                   // dcn_w -> dwT [ci*9+t][16] fp32
        if (i >= 2304) return;
        int t = i % 9, ci = (i / 9) % 16, co = i / 144;
        dwT[(ci * 9 + t) * 16 + co] = dcn_w[i];
        return;
    }
    const float* w; ushort* pk; int CIN, NT, KS;
    switch (y) {
        case 0: w = fe_w1;  pk = pf1;  CIN = 16; NT = 1; KS = 5; break;
        case 1: w = fe_w2;  pk = pf2;  CIN = 16; NT = 1; KS = 5; break;
        case 2: w = fe_w3;  pk = pf3;  CIN = 16; NT = 1; KS = 5; break;
        case 3: w = off_w0; pk = po0;  CIN = 32; NT = 1; KS = 9; break;
        case 4: w = off_w1; pk = po1;  CIN = 32; NT = 1; KS = 9; break;
        case 5: w = off_w2; pk = po2;  CIN = 32; NT = 1; KS = 9; break;
        default: w = dcn_off_w; pk = pow_; CIN = 16; NT = 9; KS = 5; break;
    }
    if (i >= KS * NT * 512) return;
    int e = i & 7, lane = (i >> 3) & 63, rest = i >> 9;
    int nt = rest % NT, ks = rest / NT;
    int k = ks * 32 + (lane >> 4) * 8 + e;
    int n = nt * 16 + (lane & 15);
    int t, ci;
    if (CIN == 16) { t = k >> 4; ci = k & 15; } else { t = k >> 5; ci = k & 31; }
    float v = (t < 9) ? w[(n * CIN + ci) * 9 + t] : 0.f;
    pk[i] = f2bf(v);
}

// ---------------- FE conv (CIN=16) on MFMA; both images via z ---------------
// output: cat buffer [pix][32] bf16 at channel offset img*16
template <bool PLANAR>
__launch_bounds__(256)
__global__ void fe_mfma_k(const float* __restrict__ pA, const float* __restrict__ pB,
                          const ushort* __restrict__ catin,
                          const ushort* __restrict__ pack, const float* __restrict__ bias,
                          ushort* __restrict__ catout,
                          int H, int W, int OH, int OW, int pad) {
    __shared__ ushort patch[324 * 16];               // [pos(18x18)][ci]
    const int tid = threadIdx.x;
    const int tx0 = blockIdx.x * 16, ty0 = blockIdx.y * 16;
    const int b = blockIdx.z & 3, img = blockIdx.z >> 2;
    const int bx = tx0 - pad, by = ty0 - pad;
    const int HW = H * W;

    if (PLANAR) {
        const float* inb = (img ? pB : pA) + (size_t)(b * 16) * HW;
        for (int pos = tid; pos < 324; pos += 256) {
            int r = pos / 18, c = pos - r * 18;
            int gy = by + r, gx = bx + c;
            bool ok = (unsigned)gy < (unsigned)H && (unsigned)gx < (unsigned)W;
            int base = gy * W + gx;
            uint o16[8];
#pragma unroll
            for (int ii = 0; ii < 8; ++ii) {
                float lo = ok ? inb[(2 * ii) * HW + base] : 0.f;
                float hi = ok ? inb[(2 * ii + 1) * HW + base] : 0.f;
                o16[ii] = (uint)f2bf(lo) | ((uint)f2bf(hi) << 16);
            }
            *(uint4*)(patch + pos * 16) = *(uint4*)&o16[0];
            *(uint4*)(patch + pos * 16 + 8) = *(uint4*)&o16[4];
        }
    } else {
        for (int c = tid; c < 648; c += 256) {
            int pos = c >> 1, h = c & 1;
            int r = pos / 18, col = pos - r * 18;
            int gy = by + r, gx = bx + col;
            uint4 v = make_uint4(0, 0, 0, 0);
            if ((unsigned)gy < (unsigned)H && (unsigned)gx < (unsigned)W)
                v = *(const uint4*)(catin + ((size_t)(b * H + gy) * W + gx) * 32 + img * 16 + h * 8);
            *(uint4*)(patch + pos * 16 + h * 8) = v;
        }
    }
    __syncthreads();

    const int lane = tid & 63, wv = tid >> 6;
    const int g = lane >> 4, ci0 = (g & 1) * 8, rowx = lane & 15;
    f32x4 acc[4];
    float bv = bias[rowx];
#pragma unroll
    for (int m = 0; m < 4; ++m) acc[m] = f32x4{bv, bv, bv, bv};

#pragma unroll
    for (int ks = 0; ks < 5; ++ks) {
        int t = 2 * ks + (g >> 1);
        int dy = t < 9 ? t / 3 : 0;
        int dx = t < 9 ? t - (t / 3) * 3 : 0;
        bf16x8 a[4];
#pragma unroll
        for (int m = 0; m < 4; ++m) {
            int r = wv * 4 + m + dy, cc = rowx + dx;
            a[m] = *(const bf16x8*)(patch + (r * 18 + cc) * 16 + ci0);
        }
        bf16x8 bfrag = *(const bf16x8*)((const uint4*)pack + ks * 64 + lane);
#pragma unroll
        for (int m = 0; m < 4; ++m)
            acc[m] = __builtin_amdgcn_mfma_f32_16x16x32_bf16(a[m], bfrag, acc[m], 0, 0, 0);
    }

    const int oxb = g * 4;
#pragma unroll
    for (int m = 0; m < 4; ++m) {
        int gy = ty0 + wv * 4 + m;
        if (gy >= OH) continue;
#pragma unroll
        for (int j = 0; j < 4; ++j) {
            int gx = tx0 + oxb + j;
            if (gx < OW)
                catout[((size_t)(b * OH + gy) * OW + gx) * 32 + img * 16 + rowx] =
                    f2bf(fmaxf(acc[m][j], 0.f));
        }
    }
}

// ---------------- offset-feature conv (CIN=32) on MFMA, 3 scales ------------
__launch_bounds__(256)
__global__ void off_mfma_k(const ushort* __restrict__ c0, const ushort* __restrict__ c1,
                           const ushort* __restrict__ c2,
                           const ushort* __restrict__ pk0, const ushort* __restrict__ pk1,
                           const ushort* __restrict__ pk2,
                           const float* __restrict__ b0, const float* __restrict__ b1,
                           const float* __restrict__ b2,
                           ushort* __restrict__ f0, ushort* __restrict__ f1,
                           ushort* __restrict__ f2) {
    const int z = blockIdx.z, s = z >> 2, b = z & 3;
    const int H = 192 - 2 * s, W = H;
    const ushort* cat  = s == 0 ? c0 : (s == 1 ? c1 : c2);
    const ushort* pack = s == 0 ? pk0 : (s == 1 ? pk1 : pk2);
    const float* bias  = s == 0 ? b0 : (s == 1 ? b1 : b2);
    ushort* out        = s == 0 ? f0 : (s == 1 ? f1 : f2);

    __shared__ ushort patch[324 * 32];               // 20.7 KB
    const int tid = threadIdx.x;
    const int tx0 = blockIdx.x * 16, ty0 = blockIdx.y * 16;
    const int bx = tx0 - 1, by = ty0 - 1;

    for (int c = tid; c < 1296; c += 256) {
        int pos = c >> 2, h = c & 3;
        int r = pos / 18, col = pos - r * 18;
        int gy = by + r, gx = bx + col;
        uint4 v = make_uint4(0, 0, 0, 0);
        if ((unsigned)gy < (unsigned)H && (unsigned)gx < (unsigned)W)
            v = *(const uint4*)(cat + ((size_t)(b * H + gy) * W + gx) * 32 + h * 8);
        *(uint4*)(patch + pos * 32 + h * 8) = v;
    }
    __syncthreads();

    const int lane = tid & 63, wv = tid >> 6;
    const int g = lane >> 4, ci0 = g * 8, rowx = lane & 15;
    f32x4 acc[4];
    float bv = bias[rowx];
#pragma unroll
    for (int m = 0; m < 4; ++m) acc[m] = f32x4{bv, bv, bv, bv};

#pragma unroll
    for (int ks = 0; ks < 9; ++ks) {                 // K = 9 taps x 32ci exactly
        int dy = ks / 3, dx = ks - (ks / 3) * 3;
        bf16x8 a[4];
#pragma unroll
        for (int m = 0; m < 4; ++m) {
            int r = wv * 4 + m + dy, cc = rowx + dx;
            a[m] = *(const bf16x8*)(patch + (r * 18 + cc) * 32 + ci0);
        }
        bf16x8 bfrag = *(const bf16x8*)((const uint4*)pack + ks * 64 + lane);
#pragma unroll
        for (int m = 0; m < 4; ++m)
            acc[m] = __builtin_amdgcn_mfma_f32_16x16x32_bf16(a[m], bfrag, acc[m], 0, 0, 0);
    }

    const int oxb = g * 4;
#pragma unroll
    for (int m = 0; m < 4; ++m) {
        int gy = ty0 + wv * 4 + m;
        if (gy >= H) continue;
#pragma unroll
        for (int j = 0; j < 4; ++j) {
            int gx = tx0 + oxb + j;
            if (gx < W)
                out[((size_t)(b * H + gy) * W + gx) * 16 + rowx] = f2bf(fmaxf(acc[m][j], 0.f));
        }
    }
}

// ------------- MFMA offset conv: off_feat bf16 -> offsets bf16 --------------
// output layout: [pix][160] bf16, dg-padded: value (dg, j) at pix*160 + dg*20 + j
__launch_bounds__(256)
__global__ void offconv_mfma_k(const ushort* __restrict__ fb0, const ushort* __restrict__ fb1,
                               const ushort* __restrict__ fb2,
                               const ushort* __restrict__ owPack, const float* __restrict__ ob,
                               ushort* __restrict__ of0, ushort* __restrict__ of1,
                               ushort* __restrict__ of2, int zbase) {
    const int z = blockIdx.z + zbase;
    const int s = z >> 2, b = z & 3;
    const int H = 192 - 2 * s, W = H;
    const ushort* fb = s == 0 ? fb0 : (s == 1 ? fb1 : fb2);
    ushort* ofs = s == 0 ? of0 : (s == 1 ? of1 : of2);

    __shared__ ushort patch[324 * 16];
    const int tid = threadIdx.x;
    const int tx0 = blockIdx.x * 16, ty0 = blockIdx.y * 16;

    for (int c = tid; c < 648; c += 256) {
        int pos = c >> 1, h = c & 1;
        int r = pos / 18, col = pos - r * 18;
        int gy = ty0 - 1 + r, gx = tx0 - 1 + col;
        uint4 v = make_uint4(0, 0, 0, 0);
        if (gy >= 0 && gy < H && gx >= 0 && gx < W)
            v = *(const uint4*)(fb + ((size_t)(b * H + gy) * W + gx) * 16 + h * 8);
        *(uint4*)(patch + pos * 16 + h * 8) = v;
    }
    __syncthreads();

    const int lane = tid & 63, wv = tid >> 6;
    const int g = lane >> 4, ci0 = (g & 1) * 8, rowx = lane & 15;

    f32x4 acc[4][9];
#pragma unroll
    for (int n = 0; n < 9; ++n) {
        float bv = ob[n * 16 + rowx];
#pragma unroll
        for (int m = 0; m < 4; ++m) acc[m][n] = f32x4{bv, bv, bv, bv};
    }

#pragma unroll
    for (int ks = 0; ks < 5; ++ks) {
        int t = 2 * ks + (g >> 1);
        int dy = t < 9 ? t / 3 : 0;
        int dx = t < 9 ? t - (t / 3) * 3 : 0;
        bf16x8 a[4];
#pragma unroll
        for (int m = 0; m < 4; ++m) {
            int r = wv * 4 + m + dy, cc = rowx + dx;
            a[m] = *(const bf16x8*)(patch + (r * 18 + cc) * 16 + ci0);
        }
        const uint4* bp = (const uint4*)owPack + (size_t)(ks * 9) * 64 + lane;
#pragma unroll
        for (int n = 0; n < 9; ++n) {
            bf16x8 bfrag = *(const bf16x8*)(bp + (size_t)n * 64);
#pragma unroll
            for (int m = 0; m < 4; ++m)
                acc[m][n] = __builtin_amdgcn_mfma_f32_16x16x32_bf16(a[m], bfrag, acc[m][n], 0, 0, 0);
        }
    }

    const int oxb = g * 4;
#pragma unroll
    for (int n = 0; n < 9; ++n) {
        int ch = n * 16 + rowx;                  // 0..143
        int dgq = ch / 18;
        int col20 = dgq * 20 + (ch - dgq * 18);
#pragma unroll
        for (int m = 0; m < 4; ++m) {
            int gy = ty0 + wv * 4 + m;
            if (gy >= H) continue;
#pragma unroll
            for (int j = 0; j < 4; ++j) {
                int gx = tx0 + oxb + j;
                if (gx < W)
                    ofs[((size_t)(b * H + gy) * W + gx) * 160 + col20] = f2bf(acc[m][n][j]);
            }
        }
    }
}

// ---------------- bilinear sampling + 16-ch deform conv accumulate ----------
// x read from bf16 cat buffer (ch 16..31); tile staged to LDS as f32 pairs.
__launch_bounds__(256)
__global__ void sample_k(const ushort* __restrict__ c0, const ushort* __restrict__ c1,
                         const ushort* __restrict__ c2,
                         const ushort* __restrict__ of0, const ushort* __restrict__ of1,
                         const ushort* __restrict__ of2,
                         const float* __restrict__ dwT, const float* __restrict__ db,
                         float* __restrict__ o0, float* __restrict__ o1,
                         float* __restrict__ o2, int zbase) {
    const int z = blockIdx.z + zbase;
    const int s = z >> 2, b = z & 3;
    const int H = 192 - 2 * s, W = H;
    const ushort* cat = s == 0 ? c0 : (s == 1 ? c1 : c2);
    const ushort* ofs = s == 0 ? of0 : (s == 1 ? of1 : of2);
    float* out = s == 0 ? o0 : (s == 1 ? o1 : o2);
    const int HW = H * W;
    const size_t pixb = (size_t)b * HW;

    __shared__ float2 xt[8][22 * 22];            // [ch pair][pos], 31 KB
    const int tid = threadIdx.x;
    const int tx0 = blockIdx.x * 16, ty0 = blockIdx.y * 16;
    const int bx = tx0 - 3, by = ty0 - 3;

    for (int pos = tid; pos < 484; pos += 256) {
        int r = pos / 22, c = pos - r * 22;
        int gy2 = by + r, gx2 = bx + c;
        uint4 va = make_uint4(0, 0, 0, 0), vb = va;
        if ((unsigned)gy2 < (unsigned)H && (unsigned)gx2 < (unsigned)W) {
            const ushort* src = cat + (pixb + gy2 * W + gx2) * 32 + 16;
            va = *(const uint4*)src;
            vb = *(const uint4*)(src + 8);
        }
        uint u[8] = {va.x, va.y, va.z, va.w, vb.x, vb.y, vb.z, vb.w};
#pragma unroll
        for (int cp = 0; cp < 8; ++cp)
            xt[cp][pos] = make_float2(bflo(u[cp]), bfhi(u[cp]));
    }
    __syncthreads();

    const int ox = tid & 15, oy = tid >> 4;
    const int gx = tx0 + ox, gy = ty0 + oy;
    const bool live = (gy < H) && (gx < W);
    const int cgy = live ? gy : H - 1, cgx = live ? gx : W - 1;
    const ushort* obase = ofs + (pixb + cgy * W + cgx) * 160;

    float acc[16];
#pragma unroll
    for (int co = 0; co < 16; ++co) acc[co] = db[co];

#pragma unroll 1
    for (int dg = 0; dg < 8; ++dg) {
        const uint2* op2 = (const uint2*)(obase + dg * 20);
        uint2 q0 = op2[0], q1 = op2[1], q2 = op2[2], q3 = op2[3];
        uint q8 = ((const uint*)op2)[8];
        uint ow[9] = {q0.x, q0.y, q1.x, q1.y, q2.x, q2.y, q3.x, q3.y, q8};
        const ushort* catg = cat + 16 + 2 * dg;
        const float2* xtd = &xt[dg][0];

#pragma unroll
        for (int k = 0; k < 9; ++k) {
            uint wo = ow[k];
            float sy = (float)(gy + k / 3 - 1) + bflo(wo);
            float sx = (float)(gx + k % 3 - 1) + bfhi(wo);
            float fy = floorf(sy), fx = floorf(sx);
            int y0 = (int)fy, x0i = (int)fx;
            float wy = sy - fy, wx = sx - fx;
            float wy1 = 1.f - wy, wx1 = 1.f - wx;
            float w00 = wy1 * wx1, w01 = wy1 * wx, w10 = wy * wx1, w11 = wy * wx;
            int ly = y0 - by, lx = x0i - bx;
            float2 v00, v01, v10, v11;
            if ((unsigned)ly <= 20u && (unsigned)lx <= 20u) {
                const float2* t = xtd + ly * 22 + lx;
                v00 = t[0]; v01 = t[1]; v10 = t[22]; v11 = t[23];
            } else {
                v00 = v01 = v10 = v11 = make_float2(0.f, 0.f);
                bool y0v = (unsigned)y0 < (unsigned)H;
                bool y1v = (unsigned)(y0 + 1) < (unsigned)H;
                bool x0v = (unsigned)x0i < (unsigned)W;
                bool x1v = (unsigned)(x0i + 1) < (unsigned)W;
                size_t i00 = (pixb + y0 * W + x0i) * 32;
                if (y0v && x0v) { uint u = *(const uint*)(catg + i00);            v00 = make_float2(bflo(u), bfhi(u)); }
                if (y0v && x1v) { uint u = *(const uint*)(catg + i00 + 32);       v01 = make_float2(bflo(u), bfhi(u)); }
                if (y1v && x0v) { uint u = *(const uint*)(catg + i00 + 32 * W);   v10 = make_float2(bflo(u), bfhi(u)); }
                if (y1v && x1v) { uint u = *(const uint*)(catg + i00 + 32 * W + 32); v11 = make_float2(bflo(u), bfhi(u)); }
            }
            float s0 = w00 * v00.x + w01 * v01.x + w10 * v10.x + w11 * v11.x;
            float s1 = w00 * v00.y + w01 * v01.y + w10 * v10.y + w11 * v11.y;
            const float* wr0 = dwT + ((2 * dg) * 9 + k) * 16;
            const float* wr1 = wr0 + 144;
#pragma unroll
            for (int co = 0; co < 16; ++co) acc[co] += s0 * wr0[co] + s1 * wr1[co];
        }
    }

    if (live) {
#pragma unroll
        for (int co = 0; co < 16; ++co)
            out[((size_t)(b * 16 + co) * H + gy) * W + gx] = acc[co];
    }
}

// ---------------------------------------------------------------------------
extern "C" void kernel_launch(void* const* d_in, const int* in_sizes, int n_in,
                              void* d_out, int out_size, void* d_ws, size_t ws_size,
                              hipStream_t stream) {
    const float* ref_image = (const float*)d_in[0];
    const float* unreg_image = (const float*)d_in[1];
    const float* fe_w1 = (const float*)d_in[2];
    const float* fe_b1 = (const float*)d_in[3];
    const float* fe_w2 = (const float*)d_in[4];
    const float* fe_b2 = (const float*)d_in[5];
    const float* fe_w3 = (const float*)d_in[6];
    const float* fe_b3 = (const float*)d_in[7];
    const float* off_w0 = (const float*)d_in[8];
    const float* off_b0 = (const float*)d_in[9];
    const float* off_w1 = (const float*)d_in[10];
    const float* off_b1 = (const float*)d_in[11];
    const float* off_w2 = (const float*)d_in[12];
    const float* off_b2 = (const float*)d_in[13];
    const float* dcn_off_w = (const float*)d_in[14];
    const float* dcn_off_b = (const float*)d_in[15];
    const float* dcn_w = (const float*)d_in[16];
    const float* dcn_b = (const float*)d_in[17];

    const size_t pix[3] = {4ul * 192 * 192, 4ul * 190 * 190, 4ul * 188 * 188};
    const size_t szf[3] = {pix[0] * 16, pix[1] * 16, pix[2] * 16};

    size_t o = 0;
    auto take = [&](size_t bytes) {
        void* r = (char*)d_ws + o;
        o += (bytes + 255) & ~(size_t)255;
        return r;
    };
    ushort* cat[3]; ushort* fb[3];
    ushort* pf[3]; ushort* po[3]; ushort* owPack; float* dwT;
    for (int s = 0; s < 3; ++s) cat[s] = (ushort*)take(pix[s] * 32 * 2);
    for (int s = 0; s < 3; ++s) fb[s] = (ushort*)take(pix[s] * 16 * 2);
    for (int s = 0; s < 3; ++s) pf[s] = (ushort*)take(2560 * 2);
    for (int s = 0; s < 3; ++s) po[s] = (ushort*)take(4608 * 2);
    owPack = (ushort*)take(23040 * 2);
    dwT = (float*)take(2304 * 4);

    // offsets ([pix][160] bf16): 3 buffers if ws allows, else 1 reused.
    ushort* offsBuf[3];
    size_t need3 = o;
    for (int s = 0; s < 3; ++s) need3 += (pix[s] * 320 + 255) & ~(size_t)255;
    bool batched = (ws_size >= need3);
    if (batched) {
        for (int s = 0; s < 3; ++s) offsBuf[s] = (ushort*)take(pix[s] * 320);
    } else {
        ushort* one = (ushort*)take(pix[0] * 320);
        offsBuf[0] = offsBuf[1] = offsBuf[2] = one;
    }

    float* out0 = (float*)d_out;
    float* out1 = out0 + szf[0];
    float* out2 = out1 + szf[1];

    dim3 blk(256);

    packall_k<<<dim3(90, 8), blk, 0, stream>>>(
        fe_w1, fe_w2, fe_w3, off_w0, off_w1, off_w2, dcn_off_w, dcn_w,
        pf[0], pf[1], pf[2], po[0], po[1], po[2], owPack, dwT);

    // FE convs (both images per launch), output -> cat buffers
    fe_mfma_k<true><<<dim3(12, 12, 8), blk, 0, stream>>>(
        ref_image, unreg_image, nullptr, pf[0], fe_b1, cat[0], 192, 192, 192, 192, 1);
    fe_mfma_k<false><<<dim3(12, 12, 8), blk, 0, stream>>>(
        nullptr, nullptr, cat[0], pf[1], fe_b2, cat[1], 192, 192, 190, 190, 0);
    fe_mfma_k<false><<<dim3(12, 12, 8), blk, 0, stream>>>(
        nullptr, nullptr, cat[1], pf[2], fe_b3, cat[2], 190, 190, 188, 188, 0);

    // offset-feature convs (all scales)
    off_mfma_k<<<dim3(12, 12, 12), blk, 0, stream>>>(
        cat[0], cat[1], cat[2], po[0], po[1], po[2],
        off_b0, off_b1, off_b2, fb[0], fb[1], fb[2]);

    if (batched) {
        offconv_mfma_k<<<dim3(12, 12, 12), blk, 0, stream>>>(
            fb[0], fb[1], fb[2], owPack, dcn_off_b,
            offsBuf[0], offsBuf[1], offsBuf[2], 0);
        sample_k<<<dim3(12, 12, 12), blk, 0, stream>>>(
            cat[0], cat[1], cat[2], offsBuf[0], offsBuf[1], offsBuf[2],
            dwT, dcn_b, out0, out1, out2, 0);
    } else {
        for (int s = 0; s < 3; ++s) {
            offconv_mfma_k<<<dim3(12, 12, 4), blk, 0, stream>>>(
                fb[0], fb[1], fb[2], owPack, dcn_off_b,
                offsBuf[0], offsBuf[1], offsBuf[2], 4 * s);
            sample_k<<<dim3(12, 12, 4), blk, 0, stream>>>(
                cat[0], cat[1], cat[2], offsBuf[0], offsBuf[1], offsBuf[2],
                dwT, dcn_b, out0, out1, out2, 4 * s);
        }
    }
}

// Round 7
// 185.133 us; speedup vs baseline: 4.3211x; 1.5088x over previous
//
#include <hip/hip_runtime.h>

typedef unsigned int uint;
typedef unsigned short ushort;
typedef __attribute__((ext_vector_type(8))) short bf16x8;
typedef __attribute__((ext_vector_type(4))) float f32x4;

__device__ inline ushort f2bf(float f) {           // f32 -> bf16 RNE
    uint u = __float_as_uint(f);
    u += 0x7fff + ((u >> 16) & 1);
    return (ushort)(u >> 16);
}
__device__ inline float bflo(uint w) { return __uint_as_float(w << 16); }
__device__ inline float bfhi(uint w) { return __uint_as_float(w & 0xffff0000u); }

// ---- pack all weights into MFMA B-fragment order (bf16) --------------------
// frag linear index i: e=i&7, lane=(i>>3)&63, rest=i>>9, nt=rest%NT, ks=rest/NT
// k = ks*32 + (lane>>4)*8 + e ; n = nt*16 + (lane&15) ; t = k/CIN ; ci = k%CIN
__global__ void packall_k(
    const float* __restrict__ fe_w1, const float* __restrict__ fe_w2,
    const float* __restrict__ fe_w3, const float* __restrict__ off_w0,
    const float* __restrict__ off_w1, const float* __restrict__ off_w2,
    const float* __restrict__ dcn_off_w, const float* __restrict__ dcn_w,
    ushort* __restrict__ pf1, ushort* __restrict__ pf2, ushort* __restrict__ pf3,
    ushort* __restrict__ po0, ushort* __restrict__ po1, ushort* __restrict__ po2,
    ushort* __restrict__ pow_, ushort* __restrict__ pd) {
    const int y = blockIdx.y;
    int i = blockIdx.x * 256 + threadIdx.x;
    const float* w; ushort* pk; int CIN, NT, KS;
    switch (y) {
        case 0: w = fe_w1;  pk = pf1;  CIN = 16; NT = 1; KS = 5; break;
        case 1: w = fe_w2;  pk = pf2;  CIN = 16; NT = 1; KS = 5; break;
        case 2: w = fe_w3;  pk = pf3;  CIN = 16; NT = 1; KS = 5; break;
        case 3: w = off_w0; pk = po0;  CIN = 32; NT = 1; KS = 9; break;
        case 4: w = off_w1; pk = po1;  CIN = 32; NT = 1; KS = 9; break;
        case 5: w = off_w2; pk = po2;  CIN = 32; NT = 1; KS = 9; break;
        case 6: w = dcn_off_w; pk = pow_; CIN = 16; NT = 9; KS = 5; break;
        default: w = dcn_w; pk = pd;   CIN = 16; NT = 1; KS = 5; break;
    }
    if (i >= KS * NT * 512) return;
    int e = i & 7, lane = (i >> 3) & 63, rest = i >> 9;
    int nt = rest % NT, ks = rest / NT;
    int k = ks * 32 + (lane >> 4) * 8 + e;
    int n = nt * 16 + (lane & 15);
    int t, ci;
    if (CIN == 16) { t = k >> 4; ci = k & 15; } else { t = k >> 5; ci = k & 31; }
    float v = (t < 9) ? w[(n * CIN + ci) * 9 + t] : 0.f;
    pk[i] = f2bf(v);
}

// ---------------- FE conv (CIN=16) on MFMA; both images via z ---------------
// output: cat buffer [pix][32] bf16 at channel offset img*16
template <bool PLANAR>
__launch_bounds__(256)
__global__ void fe_mfma_k(const float* __restrict__ pA, const float* __restrict__ pB,
                          const ushort* __restrict__ catin,
                          const ushort* __restrict__ pack, const float* __restrict__ bias,
                          ushort* __restrict__ catout,
                          int H, int W, int OH, int OW, int pad) {
    __shared__ ushort patch[324 * 16];               // [pos(18x18)][ci]
    const int tid = threadIdx.x;
    const int tx0 = blockIdx.x * 16, ty0 = blockIdx.y * 16;
    const int b = blockIdx.z & 3, img = blockIdx.z >> 2;
    const int bx = tx0 - pad, by = ty0 - pad;
    const int HW = H * W;

    if (PLANAR) {
        const float* inb = (img ? pB : pA) + (size_t)(b * 16) * HW;
        for (int pos = tid; pos < 324; pos += 256) {
            int r = pos / 18, c = pos - r * 18;
            int gy = by + r, gx = bx + c;
            bool ok = (unsigned)gy < (unsigned)H && (unsigned)gx < (unsigned)W;
            int base = gy * W + gx;
            uint o16[8];
#pragma unroll
            for (int ii = 0; ii < 8; ++ii) {
                float lo = ok ? inb[(2 * ii) * HW + base] : 0.f;
                float hi = ok ? inb[(2 * ii + 1) * HW + base] : 0.f;
                o16[ii] = (uint)f2bf(lo) | ((uint)f2bf(hi) << 16);
            }
            *(uint4*)(patch + pos * 16) = *(uint4*)&o16[0];
            *(uint4*)(patch + pos * 16 + 8) = *(uint4*)&o16[4];
        }
    } else {
        for (int c = tid; c < 648; c += 256) {
            int pos = c >> 1, h = c & 1;
            int r = pos / 18, col = pos - r * 18;
            int gy = by + r, gx = bx + col;
            uint4 v = make_uint4(0, 0, 0, 0);
            if ((unsigned)gy < (unsigned)H && (unsigned)gx < (unsigned)W)
                v = *(const uint4*)(catin + ((size_t)(b * H + gy) * W + gx) * 32 + img * 16 + h * 8);
            *(uint4*)(patch + pos * 16 + h * 8) = v;
        }
    }
    __syncthreads();

    const int lane = tid & 63, wv = tid >> 6;
    const int g = lane >> 4, ci0 = (g & 1) * 8, rowx = lane & 15;
    f32x4 acc[4];
    float bv = bias[rowx];
#pragma unroll
    for (int m = 0; m < 4; ++m) acc[m] = f32x4{bv, bv, bv, bv};

#pragma unroll
    for (int ks = 0; ks < 5; ++ks) {
        int t = 2 * ks + (g >> 1);
        int dy = t < 9 ? t / 3 : 0;
        int dx = t < 9 ? t - (t / 3) * 3 : 0;
        bf16x8 a[4];
#pragma unroll
        for (int m = 0; m < 4; ++m) {
            int r = wv * 4 + m + dy, cc = rowx + dx;
            a[m] = *(const bf16x8*)(patch + (r * 18 + cc) * 16 + ci0);
        }
        bf16x8 bfrag = *(const bf16x8*)((const uint4*)pack + ks * 64 + lane);
#pragma unroll
        for (int m = 0; m < 4; ++m)
            acc[m] = __builtin_amdgcn_mfma_f32_16x16x32_bf16(a[m], bfrag, acc[m], 0, 0, 0);
    }

    const int oxb = g * 4;
#pragma unroll
    for (int m = 0; m < 4; ++m) {
        int gy = ty0 + wv * 4 + m;
        if (gy >= OH) continue;
#pragma unroll
        for (int j = 0; j < 4; ++j) {
            int gx = tx0 + oxb + j;
            if (gx < OW)
                catout[((size_t)(b * OH + gy) * OW + gx) * 32 + img * 16 + rowx] =
                    f2bf(fmaxf(acc[m][j], 0.f));
        }
    }
}

// ---------------- offset-feature conv (CIN=32) on MFMA, 3 scales ------------
__launch_bounds__(256)
__global__ void off_mfma_k(const ushort* __restrict__ c0, const ushort* __restrict__ c1,
                           const ushort* __restrict__ c2,
                           const ushort* __restrict__ pk0, const ushort* __restrict__ pk1,
                           const ushort* __restrict__ pk2,
                           const float* __restrict__ b0, const float* __restrict__ b1,
                           const float* __restrict__ b2,
                           ushort* __restrict__ f0, ushort* __restrict__ f1,
                           ushort* __restrict__ f2) {
    const int z = blockIdx.z, s = z >> 2, b = z & 3;
    const int H = 192 - 2 * s, W = H;
    const ushort* cat  = s == 0 ? c0 : (s == 1 ? c1 : c2);
    const ushort* pack = s == 0 ? pk0 : (s == 1 ? pk1 : pk2);
    const float* bias  = s == 0 ? b0 : (s == 1 ? b1 : b2);
    ushort* out        = s == 0 ? f0 : (s == 1 ? f1 : f2);

    __shared__ ushort patch[324 * 32];               // 20.7 KB
    const int tid = threadIdx.x;
    const int tx0 = blockIdx.x * 16, ty0 = blockIdx.y * 16;
    const int bx = tx0 - 1, by = ty0 - 1;

    for (int c = tid; c < 1296; c += 256) {
        int pos = c >> 2, h = c & 3;
        int r = pos / 18, col = pos - r * 18;
        int gy = by + r, gx = bx + col;
        uint4 v = make_uint4(0, 0, 0, 0);
        if ((unsigned)gy < (unsigned)H && (unsigned)gx < (unsigned)W)
            v = *(const uint4*)(cat + ((size_t)(b * H + gy) * W + gx) * 32 + h * 8);
        *(uint4*)(patch + pos * 32 + h * 8) = v;
    }
    __syncthreads();

    const int lane = tid & 63, wv = tid >> 6;
    const int g = lane >> 4, ci0 = g * 8, rowx = lane & 15;
    f32x4 acc[4];
    float bv = bias[rowx];
#pragma unroll
    for (int m = 0; m < 4; ++m) acc[m] = f32x4{bv, bv, bv, bv};

#pragma unroll
    for (int ks = 0; ks < 9; ++ks) {                 // K = 9 taps x 32ci exactly
        int dy = ks / 3, dx = ks - (ks / 3) * 3;
        bf16x8 a[4];
#pragma unroll
        for (int m = 0; m < 4; ++m) {
            int r = wv * 4 + m + dy, cc = rowx + dx;
            a[m] = *(const bf16x8*)(patch + (r * 18 + cc) * 32 + ci0);
        }
        bf16x8 bfrag = *(const bf16x8*)((const uint4*)pack + ks * 64 + lane);
#pragma unroll
        for (int m = 0; m < 4; ++m)
            acc[m] = __builtin_amdgcn_mfma_f32_16x16x32_bf16(a[m], bfrag, acc[m], 0, 0, 0);
    }

    const int oxb = g * 4;
#pragma unroll
    for (int m = 0; m < 4; ++m) {
        int gy = ty0 + wv * 4 + m;
        if (gy >= H) continue;
#pragma unroll
        for (int j = 0; j < 4; ++j) {
            int gx = tx0 + oxb + j;
            if (gx < W)
                out[((size_t)(b * H + gy) * W + gx) * 16 + rowx] = f2bf(fmaxf(acc[m][j], 0.f));
        }
    }
}

// ------------- MFMA offset conv: off_feat bf16 -> offsets bf16 --------------
// output layout: [pix][160] bf16; value (dg, tap, comp) at pix*160 + tap*16 + dg*2 + comp
__launch_bounds__(256)
__global__ void offconv_mfma_k(const ushort* __restrict__ fb0, const ushort* __restrict__ fb1,
                               const ushort* __restrict__ fb2,
                               const ushort* __restrict__ owPack, const float* __restrict__ ob,
                               ushort* __restrict__ of0, ushort* __restrict__ of1,
                               ushort* __restrict__ of2, int zbase) {
    const int z = blockIdx.z + zbase;
    const int s = z >> 2, b = z & 3;
    const int H = 192 - 2 * s, W = H;
    const ushort* fb = s == 0 ? fb0 : (s == 1 ? fb1 : fb2);
    ushort* ofs = s == 0 ? of0 : (s == 1 ? of1 : of2);

    __shared__ ushort smem[10240];   // patch [324][16] (5184) aliased by otile [4][16][160]
    ushort* patch = smem;
    const int tid = threadIdx.x;
    const int tx0 = blockIdx.x * 16, ty0 = blockIdx.y * 16;

    for (int c = tid; c < 648; c += 256) {
        int pos = c >> 1, h = c & 1;
        int r = pos / 18, col = pos - r * 18;
        int gy = ty0 - 1 + r, gx = tx0 - 1 + col;
        uint4 v = make_uint4(0, 0, 0, 0);
        if (gy >= 0 && gy < H && gx >= 0 && gx < W)
            v = *(const uint4*)(fb + ((size_t)(b * H + gy) * W + gx) * 16 + h * 8);
        *(uint4*)(patch + pos * 16 + h * 8) = v;
    }
    __syncthreads();

    const int lane = tid & 63, wv = tid >> 6;
    const int g = lane >> 4, ci0 = (g & 1) * 8, rowx = lane & 15;

    f32x4 acc[4][9];
#pragma unroll
    for (int n = 0; n < 9; ++n) {
        float bv = ob[n * 16 + rowx];
#pragma unroll
        for (int m = 0; m < 4; ++m) acc[m][n] = f32x4{bv, bv, bv, bv};
    }

#pragma unroll
    for (int ks = 0; ks < 5; ++ks) {
        int t = 2 * ks + (g >> 1);
        int dy = t < 9 ? t / 3 : 0;
        int dx = t < 9 ? t - (t / 3) * 3 : 0;
        bf16x8 a[4];
#pragma unroll
        for (int m = 0; m < 4; ++m) {
            int r = wv * 4 + m + dy, cc = rowx + dx;
            a[m] = *(const bf16x8*)(patch + (r * 18 + cc) * 16 + ci0);
        }
        const uint4* bp = (const uint4*)owPack + (size_t)(ks * 9) * 64 + lane;
#pragma unroll
        for (int n = 0; n < 9; ++n) {
            bf16x8 bfrag = *(const bf16x8*)(bp + (size_t)n * 64);
#pragma unroll
            for (int m = 0; m < 4; ++m)
                acc[m][n] = __builtin_amdgcn_mfma_f32_16x16x32_bf16(a[m], bfrag, acc[m][n], 0, 0, 0);
        }
    }
    __syncthreads();    // all waves done reading patch; otile aliases it

    // per-wave LDS repack -> coalesced [pix][160] stores
    ushort* ot = smem + wv * 2560;                  // [16 pix][160]
    const size_t rowbytes_base = (size_t)b * H * W;
#pragma unroll
    for (int m = 0; m < 4; ++m) {
#pragma unroll
        for (int n = 0; n < 9; ++n) {
            int ch = n * 16 + rowx;                  // 0..143
            int dg = ch / 18;
            int rem = ch - dg * 18;
            int col = (rem >> 1) * 16 + dg * 2 + (rem & 1);
#pragma unroll
            for (int j = 0; j < 4; ++j)
                ot[(g * 4 + j) * 160 + col] = f2bf(acc[m][n][j]);
        }
        int py = ty0 + wv * 4 + m;
        if (py < H) {
            const uint4* src4 = (const uint4*)ot;
            uint4* dst4 = (uint4*)(ofs + (rowbytes_base + (size_t)py * W + tx0) * 160);
            for (int i = lane; i < 320; i += 64)     // 16 pix x 20 uint4
                if (tx0 + i / 20 < W) dst4[i] = src4[i];
        }
    }
}

// -------- sampling in MFMA A-frag order + MFMA deform-conv contraction ------
__launch_bounds__(256)
__global__ void sample_mfma_k(const ushort* __restrict__ c0, const ushort* __restrict__ c1,
                              const ushort* __restrict__ c2,
                              const ushort* __restrict__ of0, const ushort* __restrict__ of1,
                              const ushort* __restrict__ of2,
                              const ushort* __restrict__ pd, const float* __restrict__ db,
                              float* __restrict__ o0, float* __restrict__ o1,
                              float* __restrict__ o2, int zbase) {
    const int z = blockIdx.z + zbase;
    const int s = z >> 2, b = z & 3;
    const int H = 192 - 2 * s, W = H;
    const ushort* cat = s == 0 ? c0 : (s == 1 ? c1 : c2);
    const ushort* ofs = s == 0 ? of0 : (s == 1 ? of1 : of2);
    float* out = s == 0 ? o0 : (s == 1 ? o1 : o2);
    const int HW = H * W;
    const size_t pixb = (size_t)b * HW;

    __shared__ float2 xt[8][22 * 22];            // [ch pair][pos], 31 KB
    const int tid = threadIdx.x;
    const int tx0 = blockIdx.x * 16, ty0 = blockIdx.y * 16;
    const int bx = tx0 - 3, by = ty0 - 3;

    for (int pos = tid; pos < 484; pos += 256) {
        int r = pos / 22, c = pos - r * 22;
        int gy2 = by + r, gx2 = bx + c;
        uint4 va = make_uint4(0, 0, 0, 0), vb = va;
        if ((unsigned)gy2 < (unsigned)H && (unsigned)gx2 < (unsigned)W) {
            const ushort* src = cat + (pixb + gy2 * W + gx2) * 32 + 16;
            va = *(const uint4*)src;
            vb = *(const uint4*)(src + 8);
        }
        uint u[8] = {va.x, va.y, va.z, va.w, vb.x, vb.y, vb.z, vb.w};
#pragma unroll
        for (int cp = 0; cp < 8; ++cp)
            xt[cp][pos] = make_float2(bflo(u[cp]), bfhi(u[cp]));
    }
    __syncthreads();

    const int lane = tid & 63, wv = tid >> 6;
    const int g = lane >> 4, rowx = lane & 15, half = g & 1;
    const int px = tx0 + rowx;                   // A row (M) = image col
    const int pxc = px < W ? px : W - 1;

    f32x4 acc[4];
    float bv = db[rowx];
#pragma unroll
    for (int m = 0; m < 4; ++m) acc[m] = f32x4{bv, bv, bv, bv};

#pragma unroll 1
    for (int ks = 0; ks < 5; ++ks) {
        const int t = 2 * ks + (g >> 1);
        const bool tv = (t < 9);
        const int t3 = t / 3;
        const int ky = (tv ? t3 : 0) - 1, kx = (tv ? t - t3 * 3 : 0) - 1;

        uint4 ovm[4];
#pragma unroll
        for (int m = 0; m < 4; ++m) {
            int py = ty0 + wv * 4 + m;
            int pyc = py < H ? py : H - 1;
            ovm[m] = tv ? *(const uint4*)(ofs + (pixb + pyc * W + pxc) * 160 + t * 16 + half * 8)
                        : make_uint4(0, 0, 0, 0);
        }
        bf16x8 bfrag = *(const bf16x8*)((const uint4*)pd + ks * 64 + lane);

#pragma unroll
        for (int m = 0; m < 4; ++m) {
            const int py = ty0 + wv * 4 + m;
            uint ovv[4] = {ovm[m].x, ovm[m].y, ovm[m].z, ovm[m].w};
            uint a2[4];
            if (tv) {
#pragma unroll
                for (int d = 0; d < 4; ++d) {
                    const int dgA = half * 4 + d;
                    uint u = ovv[d];
                    float sy = (float)(py + ky) + bflo(u);
                    float sx = (float)(px + kx) + bfhi(u);
                    float fy = floorf(sy), fx = floorf(sx);
                    int y0 = (int)fy, x0 = (int)fx;
                    float wy = sy - fy, wx = sx - fx;
                    float wy1 = 1.f - wy, wx1 = 1.f - wx;
                    float w00 = wy1 * wx1, w01 = wy1 * wx, w10 = wy * wx1, w11 = wy * wx;
                    int ly = y0 - by, lx = x0 - bx;
                    float2 v00, v01, v10, v11;
                    if ((unsigned)ly <= 20u && (unsigned)lx <= 20u) {
                        const float2* tt = &xt[dgA][ly * 22 + lx];
                        v00 = tt[0]; v01 = tt[1]; v10 = tt[22]; v11 = tt[23];
                    } else {
                        v00 = v01 = v10 = v11 = make_float2(0.f, 0.f);
                        bool y0v = (unsigned)y0 < (unsigned)H;
                        bool y1v = (unsigned)(y0 + 1) < (unsigned)H;
                        bool x0v = (unsigned)x0 < (unsigned)W;
                        bool x1v = (unsigned)(x0 + 1) < (unsigned)W;
                        const ushort* cg = cat + ((size_t)pixb + (size_t)y0 * W + x0) * 32 + 16 + 2 * dgA;
                        if (y0v && x0v) { uint uu = *(const uint*)cg;                 v00 = make_float2(bflo(uu), bfhi(uu)); }
                        if (y0v && x1v) { uint uu = *(const uint*)(cg + 32);          v01 = make_float2(bflo(uu), bfhi(uu)); }
                        if (y1v && x0v) { uint uu = *(const uint*)(cg + 32 * W);      v10 = make_float2(bflo(uu), bfhi(uu)); }
                        if (y1v && x1v) { uint uu = *(const uint*)(cg + 32 * W + 32); v11 = make_float2(bflo(uu), bfhi(uu)); }
                    }
                    float s0 = w00 * v00.x + w01 * v01.x + w10 * v10.x + w11 * v11.x;
                    float s1 = w00 * v00.y + w01 * v01.y + w10 * v10.y + w11 * v11.y;
                    a2[d] = (uint)f2bf(s0) | ((uint)f2bf(s1) << 16);
                }
            } else {
                a2[0] = a2[1] = a2[2] = a2[3] = 0u;
            }
            uint4 av = make_uint4(a2[0], a2[1], a2[2], a2[3]);
            bf16x8 af = *(bf16x8*)&av;
            acc[m] = __builtin_amdgcn_mfma_f32_16x16x32_bf16(af, bfrag, acc[m], 0, 0, 0);
        }
    }

    // C store: outch = rowx, image col = g*4+j, image row = wv*4+m
#pragma unroll
    for (int m = 0; m < 4; ++m) {
        int py = ty0 + wv * 4 + m;
        if (py >= H) continue;
        float* op = out + (size_t)(b * 16 + rowx) * HW + (size_t)py * W;
#pragma unroll
        for (int j = 0; j < 4; ++j) {
            int gx2 = tx0 + g * 4 + j;
            if (gx2 < W) op[gx2] = acc[m][j];
        }
    }
}

// ---------------------------------------------------------------------------
extern "C" void kernel_launch(void* const* d_in, const int* in_sizes, int n_in,
                              void* d_out, int out_size, void* d_ws, size_t ws_size,
                              hipStream_t stream) {
    const float* ref_image = (const float*)d_in[0];
    const float* unreg_image = (const float*)d_in[1];
    const float* fe_w1 = (const float*)d_in[2];
    const float* fe_b1 = (const float*)d_in[3];
    const float* fe_w2 = (const float*)d_in[4];
    const float* fe_b2 = (const float*)d_in[5];
    const float* fe_w3 = (const float*)d_in[6];
    const float* fe_b3 = (const float*)d_in[7];
    const float* off_w0 = (const float*)d_in[8];
    const float* off_b0 = (const float*)d_in[9];
    const float* off_w1 = (const float*)d_in[10];
    const float* off_b1 = (const float*)d_in[11];
    const float* off_w2 = (const float*)d_in[12];
    const float* off_b2 = (const float*)d_in[13];
    const float* dcn_off_w = (const float*)d_in[14];
    const float* dcn_off_b = (const float*)d_in[15];
    const float* dcn_w = (const float*)d_in[16];
    const float* dcn_b = (const float*)d_in[17];

    const size_t pix[3] = {4ul * 192 * 192, 4ul * 190 * 190, 4ul * 188 * 188};
    const size_t szf[3] = {pix[0] * 16, pix[1] * 16, pix[2] * 16};

    size_t o = 0;
    auto take = [&](size_t bytes) {
        void* r = (char*)d_ws + o;
        o += (bytes + 255) & ~(size_t)255;
        return r;
    };
    ushort* cat[3]; ushort* fb[3];
    ushort* pf[3]; ushort* po[3]; ushort* owPack; ushort* pd;
    for (int s = 0; s < 3; ++s) cat[s] = (ushort*)take(pix[s] * 32 * 2);
    for (int s = 0; s < 3; ++s) fb[s] = (ushort*)take(pix[s] * 16 * 2);
    for (int s = 0; s < 3; ++s) pf[s] = (ushort*)take(2560 * 2);
    for (int s = 0; s < 3; ++s) po[s] = (ushort*)take(4608 * 2);
    owPack = (ushort*)take(23040 * 2);
    pd = (ushort*)take(2560 * 2);

    // offsets ([pix][160] bf16): 3 buffers if ws allows, else 1 reused.
    ushort* offsBuf[3];
    size_t need3 = o;
    for (int s = 0; s < 3; ++s) need3 += (pix[s] * 320 + 255) & ~(size_t)255;
    bool batched = (ws_size >= need3);
    if (batched) {
        for (int s = 0; s < 3; ++s) offsBuf[s] = (ushort*)take(pix[s] * 320);
    } else {
        ushort* one = (ushort*)take(pix[0] * 320);
        offsBuf[0] = offsBuf[1] = offsBuf[2] = one;
    }

    float* out0 = (float*)d_out;
    float* out1 = out0 + szf[0];
    float* out2 = out1 + szf[1];

    dim3 blk(256);

    packall_k<<<dim3(90, 8), blk, 0, stream>>>(
        fe_w1, fe_w2, fe_w3, off_w0, off_w1, off_w2, dcn_off_w, dcn_w,
        pf[0], pf[1], pf[2], po[0], po[1], po[2], owPack, pd);

    // FE convs (both images per launch), output -> cat buffers
    fe_mfma_k<true><<<dim3(12, 12, 8), blk, 0, stream>>>(
        ref_image, unreg_image, nullptr, pf[0], fe_b1, cat[0], 192, 192, 192, 192, 1);
    fe_mfma_k<false><<<dim3(12, 12, 8), blk, 0, stream>>>(
        nullptr, nullptr, cat[0], pf[1], fe_b2, cat[1], 192, 192, 190, 190, 0);
    fe_mfma_k<false><<<dim3(12, 12, 8), blk, 0, stream>>>(
        nullptr, nullptr, cat[1], pf[2], fe_b3, cat[2], 190, 190, 188, 188, 0);

    // offset-feature convs (all scales)
    off_mfma_k<<<dim3(12, 12, 12), blk, 0, stream>>>(
        cat[0], cat[1], cat[2], po[0], po[1], po[2],
        off_b0, off_b1, off_b2, fb[0], fb[1], fb[2]);

    if (batched) {
        offconv_mfma_k<<<dim3(12, 12, 12), blk, 0, stream>>>(
            fb[0], fb[1], fb[2], owPack, dcn_off_b,
            offsBuf[0], offsBuf[1], offsBuf[2], 0);
        sample_mfma_k<<<dim3(12, 12, 12), blk, 0, stream>>>(
            cat[0], cat[1], cat[2], offsBuf[0], offsBuf[1], offsBuf[2],
            pd, dcn_b, out0, out1, out2, 0);
    } else {
        for (int s = 0; s < 3; ++s) {
            offconv_mfma_k<<<dim3(12, 12, 4), blk, 0, stream>>>(
                fb[0], fb[1], fb[2], owPack, dcn_off_b,
                offsBuf[0], offsBuf[1], offsBuf[2], 4 * s);
            sample_mfma_k<<<dim3(12, 12, 4), blk, 0, stream>>>(
                cat[0], cat[1], cat[2], offsBuf[0], offsBuf[1], offsBuf[2],
                pd, dcn_b, out0, out1, out2, 4 * s);
        }
    }
}